// Round 1
// baseline (11362.519 us; speedup 1.0000x reference)
//
#include <hip/hip_runtime.h>
#include <cmath>

#define B_ 2
#define L_ 1024
#define D_ 768
#define DEPTH_ 6
#define DI_ 1536
#define NS_ 16
#define KC_ 4
#define R_ 48
#define FF_ 3072
#define BL_ (B_*L_)

#define OUT_XS   ((size_t)BL_*D_)
#define OUT_DTS  (OUT_XS + (size_t)DEPTH_*BL_*D_)
#define OUT_DTLR (OUT_DTS + (size_t)DEPTH_*2*BL_*DI_)

__device__ __forceinline__ float siluf(float x){ return x / (1.f + __expf(-x)); }
__device__ __forceinline__ float softplusf(float x){ return fmaxf(x,0.f) + log1pf(__expf(-fabsf(x))); }
__device__ __forceinline__ float geluf(float x){ return 0.5f*x*(1.f+erff(x*0.7071067811865475f)); }

// ---------- generic NT GEMM: C[m,n] = sum_k A[m,k]*W[n,k] (+bias/act) ----------
// epi: 0=none, 1=bias+softplus, 2=bias+gelu, 3=bias
__global__ __launch_bounds__(256) void gemm_nt(
    const float* __restrict__ A, const float* __restrict__ W,
    float* __restrict__ C, const float* __restrict__ bias,
    int M, int N, int K, int lda, int ldb, int ldc,
    long aS, long bS, long cS, long biasS, int epi)
{
    const int z = blockIdx.z;
    A += (size_t)z * aS; W += (size_t)z * bS; C += (size_t)z * cS;
    if (bias) bias += (size_t)z * biasS;
    __shared__ float As[16][68];
    __shared__ float Bs[16][68];
    const int tid = threadIdx.x;
    const int tx = tid & 15, ty = tid >> 4;
    const int row0 = blockIdx.x * 64;
    const int col0 = blockIdx.y * 64;
    float acc[4][4] = {};
    for (int k0 = 0; k0 < K; k0 += 16) {
        #pragma unroll
        for (int e = 0; e < 4; ++e) {
            int idx = tid + e*256;
            int kk = idx & 15, m = idx >> 4;
            int gm = row0 + m, gk = k0 + kk;
            As[kk][m] = (gm < M && gk < K) ? A[(size_t)gm*lda + gk] : 0.f;
            int gn = col0 + m;
            Bs[kk][m] = (gn < N && gk < K) ? W[(size_t)gn*ldb + gk] : 0.f;
        }
        __syncthreads();
        #pragma unroll
        for (int kk = 0; kk < 16; ++kk) {
            float4 a = *(const float4*)&As[kk][ty*4];
            float4 b = *(const float4*)&Bs[kk][tx*4];
            float av[4] = {a.x,a.y,a.z,a.w};
            float bv[4] = {b.x,b.y,b.z,b.w};
            #pragma unroll
            for (int i=0;i<4;i++)
                #pragma unroll
                for (int j=0;j<4;j++)
                    acc[i][j] = fmaf(av[i], bv[j], acc[i][j]);
        }
        __syncthreads();
    }
    #pragma unroll
    for (int i=0;i<4;i++){
        int gm = row0 + ty*4 + i;
        if (gm >= M) continue;
        #pragma unroll
        for (int j=0;j<4;j++){
            int gn = col0 + tx*4 + j;
            if (gn >= N) continue;
            float v = acc[i][j];
            if (epi) {
                v += bias ? bias[gn] : 0.f;
                if (epi == 1) v = softplusf(v);
                else if (epi == 2) v = geluf(v);
            }
            C[(size_t)gm*ldc + gn] = v;
        }
    }
}

// ---------- residual update + LayerNorm (ln1 path) ----------
// mode 0: residual = xprev ; mode 1: residual += xprev.  h = LN(residual)*w+b
__global__ __launch_bounds__(256) void ln_res_kernel(
    const float* __restrict__ xprev, float* __restrict__ residual,
    float* __restrict__ hout, const float* __restrict__ w,
    const float* __restrict__ bia, int mode)
{
    int row = blockIdx.x; int tid = threadIdx.x;
    __shared__ float sbuf[8];
    float v[3]; float s=0.f, ss=0.f;
    size_t base = (size_t)row*D_;
    #pragma unroll
    for (int j=0;j<3;j++){
        int c = tid + j*256;
        float x = (mode==0) ? xprev[base+c] : (residual[base+c] + xprev[base+c]);
        v[j]=x; s+=x; ss+=x*x;
        residual[base+c] = x;
    }
    for (int off=32; off; off>>=1){ s += __shfl_down(s,off); ss += __shfl_down(ss,off); }
    int wid = tid>>6, lane = tid&63;
    if (lane==0){ sbuf[wid]=s; sbuf[4+wid]=ss; }
    __syncthreads();
    if (tid==0){
        float S=sbuf[0]+sbuf[1]+sbuf[2]+sbuf[3];
        float SS=sbuf[4]+sbuf[5]+sbuf[6]+sbuf[7];
        float mean = S/(float)D_;
        float var = SS/(float)D_ - mean*mean;
        sbuf[0]=mean; sbuf[1]=rsqrtf(var+1e-5f);
    }
    __syncthreads();
    float mean=sbuf[0], inv=sbuf[1];
    #pragma unroll
    for (int j=0;j<3;j++){
        int c = tid + j*256;
        hout[base+c] = (v[j]-mean)*inv*w[c]+bia[c];
    }
}

// ---------- merge both dirs + residual + LN2 ----------
__global__ __launch_bounds__(256) void merge_ln_kernel(
    const float* __restrict__ o0, const float* __restrict__ o1,
    float* __restrict__ residual, float* __restrict__ h2,
    const float* __restrict__ w, const float* __restrict__ bia)
{
    int row = blockIdx.x; int tid = threadIdx.x;
    __shared__ float sbuf[8];
    float v[3]; float s=0.f, ss=0.f;
    size_t base = (size_t)row*D_;
    #pragma unroll
    for (int j=0;j<3;j++){
        int c = tid + j*256;
        float x = residual[base+c] + 0.5f*(o0[base+c] + o1[base+c]);
        v[j]=x; s+=x; ss+=x*x;
        residual[base+c] = x;
    }
    for (int off=32; off; off>>=1){ s += __shfl_down(s,off); ss += __shfl_down(ss,off); }
    int wid = tid>>6, lane = tid&63;
    if (lane==0){ sbuf[wid]=s; sbuf[4+wid]=ss; }
    __syncthreads();
    if (tid==0){
        float S=sbuf[0]+sbuf[1]+sbuf[2]+sbuf[3];
        float SS=sbuf[4]+sbuf[5]+sbuf[6]+sbuf[7];
        float mean = S/(float)D_;
        float var = SS/(float)D_ - mean*mean;
        sbuf[0]=mean; sbuf[1]=rsqrtf(var+1e-5f);
    }
    __syncthreads();
    float mean=sbuf[0], inv=sbuf[1];
    #pragma unroll
    for (int j=0;j<3;j++){
        int c = tid + j*256;
        h2[base+c] = (v[j]-mean)*inv*w[c]+bia[c];
    }
}

// ---------- depthwise causal conv (dir0) / anti-causal (dir1) + SiLU ----------
__global__ __launch_bounds__(256) void conv_silu_kernel(
    const float* __restrict__ xz, const float* __restrict__ conv_w,
    const float* __restrict__ conv_b, float* __restrict__ xc, int layer)
{
    int idx = blockIdx.x * 256 + threadIdx.x;
    if (idx >= 2*BL_*DI_) return;
    int d = idx % DI_;
    int bl = (idx / DI_) % BL_;
    int dir = idx / (DI_*BL_);
    int b = bl / L_, p = bl % L_;
    const float* w = conv_w + ((size_t)(layer*2+dir)*DI_ + d)*KC_;
    float acc = conv_b[(size_t)(layer*2+dir)*DI_ + d];
    const float* xp = xz + (size_t)dir*BL_*2*DI_ + d;
    #pragma unroll
    for (int k = 0; k < KC_; ++k) {
        int q = (dir == 0) ? (p - 3 + k) : (p + 3 - k);
        if (q >= 0 && q < L_)
            acc = fmaf(xp[(size_t)(b*L_+q)*2*DI_], w[k], acc);
    }
    xc[(size_t)dir*BL_*DI_ + (size_t)bl*DI_ + d] = siluf(acc);
}

// ---------- selective scan ----------
__global__ __launch_bounds__(256) void scan_kernel(
    const float* __restrict__ dt, const float* __restrict__ xdbl,
    const float* __restrict__ xc, const float* __restrict__ A_log,
    float* __restrict__ y, int layer)
{
    int bid = blockIdx.x;
    int dgrp = bid % (DI_/16);
    int b = (bid / (DI_/16)) % B_;
    int dir = bid / ((DI_/16)*B_);
    int n = threadIdx.x & 15;
    int d = dgrp*16 + (threadIdx.x >> 4);
    float Av = -__expf(A_log[(((size_t)layer*2+dir)*DI_ + d)*NS_ + n]);
    const float* dtp = dt + (size_t)dir*BL_*DI_ + (size_t)b*L_*DI_ + d;
    const float* xcp = xc + (size_t)dir*BL_*DI_ + (size_t)b*L_*DI_ + d;
    const float* xd  = xdbl + (size_t)dir*BL_*80 + (size_t)b*L_*80;
    float* yp = y + (size_t)dir*BL_*DI_ + (size_t)b*L_*DI_ + d;
    float h = 0.f;
    int p = dir ? (L_-1) : 0;
    int stp = dir ? -1 : 1;
    for (int t = 0; t < L_; ++t, p += stp) {
        float dtv = dtp[(size_t)p*DI_];
        float xv  = xcp[(size_t)p*DI_];
        float bv  = xd[p*80 + 48 + n];
        float cv  = xd[p*80 + 64 + n];
        float dA = __expf(dtv * Av);
        h = fmaf(dA, h, dtv*bv*xv);
        float yv = h * cv;
        yv += __shfl_xor(yv, 1);
        yv += __shfl_xor(yv, 2);
        yv += __shfl_xor(yv, 4);
        yv += __shfl_xor(yv, 8);
        if (n == 0) yp[(size_t)p*DI_] = yv;
    }
}

// ---------- y = (y + xc*Dp) * silu(z) ----------
__global__ __launch_bounds__(256) void gate_kernel(
    float* __restrict__ y, const float* __restrict__ xc,
    const float* __restrict__ xz, const float* __restrict__ Dp, int layer)
{
    int idx = blockIdx.x*256 + threadIdx.x;
    if (idx >= 2*BL_*DI_) return;
    int d = idx % DI_;
    int bl = (idx / DI_) % BL_;
    int dir = idx / (DI_*BL_);
    float z = xz[(size_t)dir*BL_*2*DI_ + (size_t)bl*2*DI_ + DI_ + d];
    float v = y[idx] + xc[idx]*Dp[(size_t)(layer*2+dir)*DI_ + d];
    y[idx] = v * siluf(z);
}

// ---------- scatter dt to output (dir1 time-flipped) ----------
__global__ __launch_bounds__(256) void scatter_dts(
    const float* __restrict__ dtw, float* __restrict__ out, int layer)
{
    int idx = blockIdx.x*256 + threadIdx.x;
    if (idx >= 2*BL_*DI_) return;
    int d = idx % DI_;
    int bl = (idx / DI_) % BL_;
    int dir = idx / (DI_*BL_);
    int b = bl / L_, p = bl % L_;
    int t = dir ? (L_-1-p) : p;
    out[OUT_DTS + ((((size_t)layer*2+dir)*B_ + b)*L_ + t)*DI_ + d] = dtw[idx];
}

__global__ __launch_bounds__(256) void scatter_dtlr(
    const float* __restrict__ xdbl, float* __restrict__ out, int layer)
{
    int idx = blockIdx.x*256 + threadIdx.x;
    if (idx >= 2*BL_*R_) return;
    int r = idx % R_;
    int bl = (idx / R_) % BL_;
    int dir = idx / (R_*BL_);
    int b = bl / L_, p = bl % L_;
    int t = dir ? (L_-1-p) : p;
    out[OUT_DTLR + ((((size_t)layer*2+dir)*B_ + b)*L_ + t)*R_ + r] =
        xdbl[(size_t)dir*BL_*80 + (size_t)bl*80 + r];
}

__global__ __launch_bounds__(256) void copy_kernel(
    const float* __restrict__ src, float* __restrict__ dst, int n)
{
    int idx = blockIdx.x*256 + threadIdx.x;
    if (idx < n) dst[idx] = src[idx];
}

extern "C" void kernel_launch(void* const* d_in, const int* in_sizes, int n_in,
                              void* d_out, int out_size, void* d_ws, size_t ws_size,
                              hipStream_t stream)
{
    const float* x_in    = (const float*)d_in[0];
    const float* ln1_w   = (const float*)d_in[1];
    const float* ln1_b   = (const float*)d_in[2];
    const float* ln2_w   = (const float*)d_in[3];
    const float* ln2_b   = (const float*)d_in[4];
    const float* in_w    = (const float*)d_in[5];
    const float* conv_w  = (const float*)d_in[6];
    const float* conv_b  = (const float*)d_in[7];
    const float* xproj_w = (const float*)d_in[8];
    const float* dtproj_w= (const float*)d_in[9];
    const float* dtproj_b= (const float*)d_in[10];
    const float* A_log   = (const float*)d_in[11];
    const float* D_param = (const float*)d_in[12];
    const float* out_w   = (const float*)d_in[13];
    const float* mlp_w1  = (const float*)d_in[14];
    const float* mlp_b1  = (const float*)d_in[15];
    const float* mlp_w2  = (const float*)d_in[16];
    const float* mlp_b2  = (const float*)d_in[17];

    float* out = (float*)d_out;
    float* ws  = (float*)d_ws;
    float* res  = ws;
    float* h    = res  + (size_t)BL_*D_;
    float* xz   = h    + (size_t)BL_*D_;        // 2 * BL * 2DI
    float* xc   = xz   + (size_t)2*BL_*2*DI_;   // 2 * BL * DI
    float* xdbl = xc   + (size_t)2*BL_*DI_;     // 2 * BL * 80
    float* dtw  = xdbl + (size_t)2*BL_*80;      // 2 * BL * DI
    float* yb   = dtw  + (size_t)2*BL_*DI_;     // 2 * BL * DI
    float* ob   = yb   + (size_t)2*BL_*DI_;     // 2 * BL * D
    float* h2   = ob   + (size_t)2*BL_*D_;      // BL * D
    float* hid  = h2   + (size_t)BL_*D_;        // BL * FF

    for (int i = 0; i < DEPTH_; ++i) {
        const float* xprev = (i==0) ? x_in : (out + OUT_XS + (size_t)(i-1)*BL_*D_);
        ln_res_kernel<<<BL_, 256, 0, stream>>>(xprev, res, h,
            ln1_w + (size_t)i*D_, ln1_b + (size_t)i*D_, (i==0)?0:1);

        dim3 gIn(BL_/64, (2*DI_)/64, 2);
        gemm_nt<<<gIn, 256, 0, stream>>>(h, in_w + (size_t)i*2*(2*DI_)*D_, xz, nullptr,
            BL_, 2*DI_, D_, D_, D_, 2*DI_,
            0L, (long)(2*DI_)*D_, (long)BL_*2*DI_, 0L, 0);

        conv_silu_kernel<<<(2*BL_*DI_+255)/256, 256, 0, stream>>>(xz, conv_w, conv_b, xc, i);

        dim3 gXp(BL_/64, 2, 2);
        gemm_nt<<<gXp, 256, 0, stream>>>(xc, xproj_w + (size_t)i*2*80*DI_, xdbl, nullptr,
            BL_, 80, DI_, DI_, DI_, 80,
            (long)BL_*DI_, (long)80*DI_, (long)BL_*80, 0L, 0);

        dim3 gDt(BL_/64, DI_/64, 2);
        gemm_nt<<<gDt, 256, 0, stream>>>(xdbl, dtproj_w + (size_t)i*2*DI_*R_, dtw,
            dtproj_b + (size_t)i*2*DI_,
            BL_, DI_, R_, 80, R_, DI_,
            (long)BL_*80, (long)DI_*R_, (long)BL_*DI_, (long)DI_, 1);

        scatter_dts<<<(2*BL_*DI_+255)/256, 256, 0, stream>>>(dtw, out, i);
        scatter_dtlr<<<(2*BL_*R_+255)/256, 256, 0, stream>>>(xdbl, out, i);

        scan_kernel<<<2*B_*(DI_/16), 256, 0, stream>>>(dtw, xdbl, xc, A_log, yb, i);

        gate_kernel<<<(2*BL_*DI_+255)/256, 256, 0, stream>>>(yb, xc, xz, D_param, i);

        dim3 gOut(BL_/64, D_/64, 2);
        gemm_nt<<<gOut, 256, 0, stream>>>(yb, out_w + (size_t)i*2*D_*DI_, ob, nullptr,
            BL_, D_, DI_, DI_, DI_, D_,
            (long)BL_*DI_, (long)D_*DI_, (long)BL_*D_, 0L, 0);

        merge_ln_kernel<<<BL_, 256, 0, stream>>>(ob, ob + (size_t)BL_*D_, res, h2,
            ln2_w + (size_t)i*D_, ln2_b + (size_t)i*D_);

        dim3 gM1(BL_/64, FF_/64, 1);
        gemm_nt<<<gM1, 256, 0, stream>>>(h2, mlp_w1 + (size_t)i*FF_*D_, hid,
            mlp_b1 + (size_t)i*FF_,
            BL_, FF_, D_, D_, D_, FF_, 0L, 0L, 0L, 0L, 2);

        dim3 gM2(BL_/64, D_/64, 1);
        gemm_nt<<<gM2, 256, 0, stream>>>(hid, mlp_w2 + (size_t)i*D_*FF_,
            out + OUT_XS + (size_t)i*BL_*D_, mlp_b2 + (size_t)i*D_,
            BL_, D_, FF_, FF_, FF_, D_, 0L, 0L, 0L, 0L, 3);
    }

    copy_kernel<<<(BL_*D_+255)/256, 256, 0, stream>>>(
        out + OUT_XS + (size_t)(DEPTH_-1)*BL_*D_, out, BL_*D_);
}

// Round 2
// 2778.490 us; speedup vs baseline: 4.0895x; 4.0895x over previous
//
#include <hip/hip_runtime.h>
#include <cmath>

#define B_ 2
#define L_ 1024
#define D_ 768
#define DEPTH_ 6
#define DI_ 1536
#define NS_ 16
#define KC_ 4
#define R_ 48
#define FF_ 3072
#define BL_ (B_*L_)
#define CH_ 16
#define NDG_ (DI_/16)

#define OUT_XS   ((size_t)BL_*D_)
#define OUT_DTS  (OUT_XS + (size_t)DEPTH_*BL_*D_)
#define OUT_DTLR (OUT_DTS + (size_t)DEPTH_*2*BL_*DI_)

typedef unsigned short u16;
typedef unsigned int u32;
typedef __bf16 bf16x8 __attribute__((ext_vector_type(8)));
typedef float f32x4 __attribute__((ext_vector_type(4)));

__device__ __forceinline__ float siluf(float x){ return x / (1.f + __expf(-x)); }
__device__ __forceinline__ float softplusf(float x){ return fmaxf(x,0.f) + log1pf(__expf(-fabsf(x))); }
__device__ __forceinline__ float geluf(float x){ return 0.5f*x*(1.f+erff(x*0.7071067811865475f)); }
__device__ __forceinline__ u32 f2bf(float f){
    u32 u = __float_as_uint(f);
    return (u + 0x7FFFu + ((u>>16)&1u)) >> 16;
}

// ---------------- fp32 -> bf16 conversion (4 elems/thread) ----------------
__global__ __launch_bounds__(256) void cvt_bf16(const float* __restrict__ in,
                                                u16* __restrict__ out, int n4)
{
    int i = blockIdx.x*256 + threadIdx.x;
    if (i >= n4) return;
    float4 v = ((const float4*)in)[i];
    uint2 o;
    o.x = f2bf(v.x) | (f2bf(v.y) << 16);
    o.y = f2bf(v.z) | (f2bf(v.w) << 16);
    ((uint2*)out)[i] = o;
}

// ---------------- bf16 MFMA GEMM: C[m,n] = sum_k A[m,k]*Bw[n,k] ----------------
// 128x128 tile, BK=64, 4 waves (2x2), 16x16x32 MFMA. All dims multiples required.
// KS>1: writes fp32 partials to C at stride cS per (zb*KS+sk), no epilogue.
template<int EPI, int OUTBF>
__global__ __launch_bounds__(256) void gemm_bf16(
    const u16* __restrict__ A, const u16* __restrict__ Bw,
    float* __restrict__ C, u16* __restrict__ Cbf, const float* __restrict__ bias,
    int M, int N, int K, int KS, long aS, long bS, long cS)
{
    const int zAll = blockIdx.z;
    const int sk = zAll % KS, zb = zAll / KS;
    A  += (size_t)zb * aS;
    Bw += (size_t)zb * bS;
    __shared__ u16 As[128*64];
    __shared__ u16 Bs[128*64];
    const int tid = threadIdx.x;
    const int w = tid >> 6, l = tid & 63;
    const int wr = w >> 1, wc = w & 1;
    const int row0 = blockIdx.x * 128, col0 = blockIdx.y * 128;
    const int Ksl = K / KS;
    const int kbeg = sk * Ksl;
    const int srow = l >> 3;        // row within 8-row chunk
    const int scol = (l & 7) * 8;   // k element offset
    f32x4 acc[4][4] = {};
    for (int k0 = kbeg; k0 < kbeg + Ksl; k0 += 64) {
        #pragma unroll
        for (int c = 0; c < 4; ++c) {
            int chunk = w*4 + c;
            const u16* ga = A + (size_t)(row0 + chunk*8 + srow) * K + (k0 + scol);
            __builtin_amdgcn_global_load_lds(
                (const __attribute__((address_space(1))) void*)ga,
                (__attribute__((address_space(3))) void*)(As + chunk*512), 16, 0, 0);
            const u16* gb = Bw + (size_t)(col0 + chunk*8 + srow) * K + (k0 + scol);
            __builtin_amdgcn_global_load_lds(
                (const __attribute__((address_space(1))) void*)gb,
                (__attribute__((address_space(3))) void*)(Bs + chunk*512), 16, 0, 0);
        }
        __syncthreads();
        #pragma unroll
        for (int kk = 0; kk < 64; kk += 32) {
            bf16x8 af[4], bfr[4];
            #pragma unroll
            for (int m = 0; m < 4; ++m)
                af[m] = *(const bf16x8*)(As + (wr*64 + m*16 + (l&15))*64 + kk + (l>>4)*8);
            #pragma unroll
            for (int n = 0; n < 4; ++n)
                bfr[n] = *(const bf16x8*)(Bs + (wc*64 + n*16 + (l&15))*64 + kk + (l>>4)*8);
            #pragma unroll
            for (int m = 0; m < 4; ++m)
                #pragma unroll
                for (int n = 0; n < 4; ++n)
                    acc[m][n] = __builtin_amdgcn_mfma_f32_16x16x32_bf16(af[m], bfr[n], acc[m][n], 0, 0, 0);
        }
        __syncthreads();
    }
    if (KS > 1) {
        float* Cp = C + (size_t)(zb*KS + sk) * cS;
        #pragma unroll
        for (int m = 0; m < 4; ++m)
            #pragma unroll
            for (int j = 0; j < 4; ++j) {
                int r = row0 + wr*64 + m*16 + (l>>4)*4 + j;
                #pragma unroll
                for (int n = 0; n < 4; ++n) {
                    int col = col0 + wc*64 + n*16 + (l&15);
                    Cp[(size_t)r*N + col] = acc[m][n][j];
                }
            }
    } else {
        float* Cz = C + (size_t)zb * cS;
        #pragma unroll
        for (int m = 0; m < 4; ++m)
            #pragma unroll
            for (int j = 0; j < 4; ++j) {
                int r = row0 + wr*64 + m*16 + (l>>4)*4 + j;
                #pragma unroll
                for (int n = 0; n < 4; ++n) {
                    int col = col0 + wc*64 + n*16 + (l&15);
                    float v = acc[m][n][j];
                    if (EPI == 2) v = geluf(v + bias[col]);
                    else if (EPI == 3) v += bias[col];
                    if (OUTBF) Cbf[(size_t)r*N + col] = (u16)f2bf(v);
                    else       Cz[(size_t)r*N + col] = v;
                }
            }
    }
}

// ---------------- split-K partial reduce (+bias) ----------------
template<int EPI>
__global__ __launch_bounds__(256) void reduce_k(
    const float* __restrict__ part, float* __restrict__ C,
    const float* __restrict__ bias, int MN, int N, int KS)
{
    int zb = blockIdx.y;
    int idx = blockIdx.x*256 + threadIdx.x;
    if (idx >= MN) return;
    const float* p = part + (size_t)zb*KS*MN;
    float s = 0.f;
    for (int sk = 0; sk < KS; ++sk) s += p[(size_t)sk*MN + idx];
    if (EPI == 3) s += bias[idx % N];
    C[(size_t)zb*MN + idx] = s;
}

// ---------------- fp32 NT GEMM (small shapes). KS>1 -> atomicAdd partials ----------------
// epi: 0=none, 1=bias+softplus
__global__ __launch_bounds__(256) void gemm_nt(
    const float* __restrict__ A, const float* __restrict__ W,
    float* __restrict__ C, const float* __restrict__ bias,
    int M, int N, int K, int lda, int ldb, int ldc,
    long aS, long bS, long cS, long biasS, int epi, int KS)
{
    const int zAll = blockIdx.z;
    const int sk = zAll % KS, zb = zAll / KS;
    A += (size_t)zb * aS; W += (size_t)zb * bS; C += (size_t)zb * cS;
    if (bias) bias += (size_t)zb * biasS;
    __shared__ float As[16][68];
    __shared__ float Bs[16][68];
    const int tid = threadIdx.x;
    const int tx = tid & 15, ty = tid >> 4;
    const int row0 = blockIdx.x * 64;
    const int col0 = blockIdx.y * 64;
    const int Ksl = K / KS;
    float acc[4][4] = {};
    for (int k0 = sk*Ksl; k0 < sk*Ksl + Ksl; k0 += 16) {
        #pragma unroll
        for (int e = 0; e < 4; ++e) {
            int idx = tid + e*256;
            int kk = idx & 15, m = idx >> 4;
            int gm = row0 + m, gk = k0 + kk;
            As[kk][m] = (gm < M && gk < K) ? A[(size_t)gm*lda + gk] : 0.f;
            int gn = col0 + m;
            Bs[kk][m] = (gn < N && gk < K) ? W[(size_t)gn*ldb + gk] : 0.f;
        }
        __syncthreads();
        #pragma unroll
        for (int kk = 0; kk < 16; ++kk) {
            float4 a = *(const float4*)&As[kk][ty*4];
            float4 b = *(const float4*)&Bs[kk][tx*4];
            float av[4] = {a.x,a.y,a.z,a.w};
            float bv[4] = {b.x,b.y,b.z,b.w};
            #pragma unroll
            for (int i=0;i<4;i++)
                #pragma unroll
                for (int j=0;j<4;j++)
                    acc[i][j] = fmaf(av[i], bv[j], acc[i][j]);
        }
        __syncthreads();
    }
    #pragma unroll
    for (int i=0;i<4;i++){
        int gm = row0 + ty*4 + i;
        if (gm >= M) continue;
        #pragma unroll
        for (int j=0;j<4;j++){
            int gn = col0 + tx*4 + j;
            if (gn >= N) continue;
            float v = acc[i][j];
            if (KS > 1) { atomicAdd(&C[(size_t)gm*ldc + gn], v); continue; }
            if (epi) {
                v += bias ? bias[gn] : 0.f;
                if (epi == 1) v = softplusf(v);
            }
            C[(size_t)gm*ldc + gn] = v;
        }
    }
}

__global__ __launch_bounds__(256) void zero_kernel(float* __restrict__ p, int n)
{
    int i = blockIdx.x*256 + threadIdx.x;
    if (i < n) p[i] = 0.f;
}

// ---------------- residual + LN1 -> bf16 h ----------------
__global__ __launch_bounds__(256) void ln_res_kernel(
    const float* __restrict__ xprev, float* __restrict__ residual,
    u16* __restrict__ hout, const float* __restrict__ w,
    const float* __restrict__ bia, int mode)
{
    int row = blockIdx.x; int tid = threadIdx.x;
    __shared__ float sbuf[8];
    float v[3]; float s=0.f, ss=0.f;
    size_t base = (size_t)row*D_;
    #pragma unroll
    for (int j=0;j<3;j++){
        int c = tid + j*256;
        float x = (mode==0) ? xprev[base+c] : (residual[base+c] + xprev[base+c]);
        v[j]=x; s+=x; ss+=x*x;
        residual[base+c] = x;
    }
    for (int off=32; off; off>>=1){ s += __shfl_down(s,off); ss += __shfl_down(ss,off); }
    int wid = tid>>6, lane = tid&63;
    if (lane==0){ sbuf[wid]=s; sbuf[4+wid]=ss; }
    __syncthreads();
    if (tid==0){
        float S=sbuf[0]+sbuf[1]+sbuf[2]+sbuf[3];
        float SS=sbuf[4]+sbuf[5]+sbuf[6]+sbuf[7];
        float mean = S/(float)D_;
        float var = SS/(float)D_ - mean*mean;
        sbuf[0]=mean; sbuf[1]=rsqrtf(var+1e-5f);
    }
    __syncthreads();
    float mean=sbuf[0], inv=sbuf[1];
    #pragma unroll
    for (int j=0;j<3;j++){
        int c = tid + j*256;
        hout[base+c] = (u16)f2bf((v[j]-mean)*inv*w[c]+bia[c]);
    }
}

// ---------------- merge dirs + residual + LN2 -> bf16 h2 ----------------
__global__ __launch_bounds__(256) void merge_ln_kernel(
    const float* __restrict__ o0, const float* __restrict__ o1,
    float* __restrict__ residual, u16* __restrict__ h2,
    const float* __restrict__ w, const float* __restrict__ bia)
{
    int row = blockIdx.x; int tid = threadIdx.x;
    __shared__ float sbuf[8];
    float v[3]; float s=0.f, ss=0.f;
    size_t base = (size_t)row*D_;
    #pragma unroll
    for (int j=0;j<3;j++){
        int c = tid + j*256;
        float x = residual[base+c] + 0.5f*(o0[base+c] + o1[base+c]);
        v[j]=x; s+=x; ss+=x*x;
        residual[base+c] = x;
    }
    for (int off=32; off; off>>=1){ s += __shfl_down(s,off); ss += __shfl_down(ss,off); }
    int wid = tid>>6, lane = tid&63;
    if (lane==0){ sbuf[wid]=s; sbuf[4+wid]=ss; }
    __syncthreads();
    if (tid==0){
        float S=sbuf[0]+sbuf[1]+sbuf[2]+sbuf[3];
        float SS=sbuf[4]+sbuf[5]+sbuf[6]+sbuf[7];
        float mean = S/(float)D_;
        float var = SS/(float)D_ - mean*mean;
        sbuf[0]=mean; sbuf[1]=rsqrtf(var+1e-5f);
    }
    __syncthreads();
    float mean=sbuf[0], inv=sbuf[1];
    #pragma unroll
    for (int j=0;j<3;j++){
        int c = tid + j*256;
        h2[base+c] = (u16)f2bf((v[j]-mean)*inv*w[c]+bia[c]);
    }
}

// ---------------- depthwise conv + SiLU ----------------
__global__ __launch_bounds__(256) void conv_silu_kernel(
    const float* __restrict__ xz, const float* __restrict__ conv_w,
    const float* __restrict__ conv_b, float* __restrict__ xc, int layer)
{
    int idx = blockIdx.x * 256 + threadIdx.x;
    if (idx >= 2*BL_*DI_) return;
    int d = idx % DI_;
    int bl = (idx / DI_) % BL_;
    int dir = idx / (DI_*BL_);
    int b = bl / L_, p = bl % L_;
    const float* w = conv_w + ((size_t)(layer*2+dir)*DI_ + d)*KC_;
    float acc = conv_b[(size_t)(layer*2+dir)*DI_ + d];
    const float* xp = xz + (size_t)dir*BL_*2*DI_ + d;
    #pragma unroll
    for (int k = 0; k < KC_; ++k) {
        int q = (dir == 0) ? (p - 3 + k) : (p + 3 - k);
        if (q >= 0 && q < L_)
            acc = fmaf(xp[(size_t)(b*L_+q)*2*DI_], w[k], acc);
    }
    xc[(size_t)dir*BL_*DI_ + (size_t)bl*DI_ + d] = siluf(acc);
}

// ---------------- chunked scan: phase 1 (per-chunk h, prod(dA)) ----------------
__global__ __launch_bounds__(256) void scan_part(
    const float* __restrict__ dt, const float* __restrict__ xdbl,
    const float* __restrict__ xc, const float* __restrict__ A_log,
    float* __restrict__ hp, float* __restrict__ Pp, int layer)
{
    int bid = blockIdx.x;
    int dgrp = bid % NDG_;
    int chunk = (bid / NDG_) % CH_;
    int b = (bid / (NDG_*CH_)) % B_;
    int dir = bid / (NDG_*CH_*B_);
    __shared__ float sdt[64][16], sxc[64][16], sB[64][16];
    int tid = threadIdx.x;
    const size_t rowbase = (size_t)dir*BL_ + (size_t)b*L_;
    #pragma unroll
    for (int e = 0; e < 4; ++e) {
        int idx = tid + e*256;
        int s = idx >> 4, dl = idx & 15;
        int p = dir ? (L_-1-(chunk*64+s)) : (chunk*64+s);
        sdt[s][dl] = dt[(rowbase+p)*DI_ + dgrp*16 + dl];
        sxc[s][dl] = xc[(rowbase+p)*DI_ + dgrp*16 + dl];
        sB[s][dl]  = xdbl[(rowbase+p)*80 + 48 + dl];
    }
    __syncthreads();
    int dsub = tid >> 4, n = tid & 15;
    int d = dgrp*16 + dsub;
    float Av = -__expf(A_log[(((size_t)layer*2+dir)*DI_ + d)*NS_ + n]);
    float h = 0.f, P = 1.f;
    for (int s = 0; s < 64; ++s) {
        float dtv = sdt[s][dsub];
        float dA = __expf(dtv*Av);
        P *= dA;
        h = fmaf(dA, h, dtv*sB[s][n]*sxc[s][dsub]);
    }
    size_t idx = (((size_t)(dir*B_+b)*CH_ + chunk)*DI_ + d)*16 + n;
    hp[idx] = h; Pp[idx] = P;
}

// ---------------- phase 2: sequential combine over chunks (hp -> h_init) ----------------
__global__ __launch_bounds__(256) void scan_combine(
    float* __restrict__ hp, const float* __restrict__ Pp)
{
    int bid = blockIdx.x;
    int dgrp = bid % NDG_;
    int b = (bid / NDG_) % B_;
    int dir = bid / (NDG_*B_);
    int tid = threadIdx.x;
    int d = dgrp*16 + (tid >> 4), n = tid & 15;
    size_t base = (size_t)(dir*B_+b)*CH_;
    float h = 0.f;
    for (int c = 0; c < CH_; ++c) {
        size_t idx = ((base + c)*DI_ + d)*16 + n;
        float P = Pp[idx], hl = hp[idx];
        hp[idx] = h;            // h_init for chunk c
        h = fmaf(P, h, hl);
    }
}

// ---------------- phase 3: recompute with h_init, produce y (y may alias dt) ----------------
__global__ __launch_bounds__(256) void scan_final(
    const float* dt, const float* __restrict__ xdbl,
    const float* __restrict__ xc, const float* __restrict__ A_log,
    const float* __restrict__ hp, float* y, int layer)
{
    int bid = blockIdx.x;
    int dgrp = bid % NDG_;
    int chunk = (bid / NDG_) % CH_;
    int b = (bid / (NDG_*CH_)) % B_;
    int dir = bid / (NDG_*CH_*B_);
    __shared__ float sdt[64][16], sxc[64][16], sB[64][16], sC[64][16], sY[64][16];
    int tid = threadIdx.x;
    const size_t rowbase = (size_t)dir*BL_ + (size_t)b*L_;
    #pragma unroll
    for (int e = 0; e < 4; ++e) {
        int idx = tid + e*256;
        int s = idx >> 4, dl = idx & 15;
        int p = dir ? (L_-1-(chunk*64+s)) : (chunk*64+s);
        sdt[s][dl] = dt[(rowbase+p)*DI_ + dgrp*16 + dl];
        sxc[s][dl] = xc[(rowbase+p)*DI_ + dgrp*16 + dl];
        sB[s][dl]  = xdbl[(rowbase+p)*80 + 48 + dl];
        sC[s][dl]  = xdbl[(rowbase+p)*80 + 64 + dl];
    }
    __syncthreads();
    int dsub = tid >> 4, n = tid & 15;
    int d = dgrp*16 + dsub;
    float Av = -__expf(A_log[(((size_t)layer*2+dir)*DI_ + d)*NS_ + n]);
    float h = hp[(((size_t)(dir*B_+b)*CH_ + chunk)*DI_ + d)*16 + n];
    for (int s = 0; s < 64; ++s) {
        float dtv = sdt[s][dsub];
        float dA = __expf(dtv*Av);
        h = fmaf(dA, h, dtv*sB[s][n]*sxc[s][dsub]);
        float yv = h * sC[s][n];
        yv += __shfl_xor(yv, 1);
        yv += __shfl_xor(yv, 2);
        yv += __shfl_xor(yv, 4);
        yv += __shfl_xor(yv, 8);
        if (n == 0) sY[s][dsub] = yv;
    }
    __syncthreads();
    #pragma unroll
    for (int e = 0; e < 4; ++e) {
        int idx = tid + e*256;
        int s = idx >> 4, dl = idx & 15;
        int p = dir ? (L_-1-(chunk*64+s)) : (chunk*64+s);
        y[(rowbase+p)*DI_ + dgrp*16 + dl] = sY[s][dl];
    }
}

// ---------------- gate: yb_bf = f2bf((y + xc*Dp) * silu(z)) ----------------
__global__ __launch_bounds__(256) void gate_kernel(
    const float* __restrict__ y, const float* __restrict__ xc,
    const float* __restrict__ xz, const float* __restrict__ Dp,
    u16* __restrict__ ybbf, int layer)
{
    int idx = blockIdx.x*256 + threadIdx.x;
    if (idx >= 2*BL_*DI_) return;
    int d = idx % DI_;
    int bl = (idx / DI_) % BL_;
    int dir = idx / (DI_*BL_);
    float z = xz[(size_t)dir*BL_*2*DI_ + (size_t)bl*2*DI_ + DI_ + d];
    float v = y[idx] + xc[idx]*Dp[(size_t)(layer*2+dir)*DI_ + d];
    ybbf[idx] = (u16)f2bf(v * siluf(z));
}

// ---------------- scatter outputs (dir1 time-flipped) ----------------
__global__ __launch_bounds__(256) void scatter_dts(
    const float* __restrict__ dtw, float* __restrict__ out, int layer)
{
    int idx = blockIdx.x*256 + threadIdx.x;
    if (idx >= 2*BL_*DI_) return;
    int d = idx % DI_;
    int bl = (idx / DI_) % BL_;
    int dir = idx / (DI_*BL_);
    int b = bl / L_, p = bl % L_;
    int t = dir ? (L_-1-p) : p;
    out[OUT_DTS + ((((size_t)layer*2+dir)*B_ + b)*L_ + t)*DI_ + d] = dtw[idx];
}

__global__ __launch_bounds__(256) void scatter_dtlr(
    const float* __restrict__ xdbl, float* __restrict__ out, int layer)
{
    int idx = blockIdx.x*256 + threadIdx.x;
    if (idx >= 2*BL_*R_) return;
    int r = idx % R_;
    int bl = (idx / R_) % BL_;
    int dir = idx / (R_*BL_);
    int b = bl / L_, p = bl % L_;
    int t = dir ? (L_-1-p) : p;
    out[OUT_DTLR + ((((size_t)layer*2+dir)*B_ + b)*L_ + t)*R_ + r] =
        xdbl[(size_t)dir*BL_*80 + (size_t)bl*80 + r];
}

__global__ __launch_bounds__(256) void copy_kernel(
    const float* __restrict__ src, float* __restrict__ dst, int n)
{
    int idx = blockIdx.x*256 + threadIdx.x;
    if (idx < n) dst[idx] = src[idx];
}

extern "C" void kernel_launch(void* const* d_in, const int* in_sizes, int n_in,
                              void* d_out, int out_size, void* d_ws, size_t ws_size,
                              hipStream_t stream)
{
    const float* x_in    = (const float*)d_in[0];
    const float* ln1_w   = (const float*)d_in[1];
    const float* ln1_b   = (const float*)d_in[2];
    const float* ln2_w   = (const float*)d_in[3];
    const float* ln2_b   = (const float*)d_in[4];
    const float* in_w    = (const float*)d_in[5];
    const float* conv_w  = (const float*)d_in[6];
    const float* conv_b  = (const float*)d_in[7];
    const float* xproj_w = (const float*)d_in[8];
    const float* dtproj_w= (const float*)d_in[9];
    const float* dtproj_b= (const float*)d_in[10];
    const float* A_log   = (const float*)d_in[11];
    const float* D_param = (const float*)d_in[12];
    const float* out_w   = (const float*)d_in[13];
    const float* mlp_w1  = (const float*)d_in[14];
    const float* mlp_b1  = (const float*)d_in[15];
    const float* mlp_w2  = (const float*)d_in[16];
    const float* mlp_b2  = (const float*)d_in[17];

    float* out = (float*)d_out;
    float* ws  = (float*)d_ws;

    const size_t SCAN_ST = (size_t)2*B_*CH_*DI_*16;
    float* res  = ws;
    float* xz   = res  + (size_t)BL_*D_;        // 2*BL*2DI (ob + partials alias here)
    float* xc   = xz   + (size_t)2*BL_*2*DI_;
    float* xdbl = xc   + (size_t)2*BL_*DI_;     // 2*BL*80
    float* dtw  = xdbl + (size_t)2*BL_*80;      // 2*BL*DI (y aliases)
    float* hp   = dtw  + (size_t)2*BL_*DI_;
    float* Pp   = hp   + SCAN_ST;
    u16* h_bf   = (u16*)(Pp + SCAN_ST);
    u16* yb_bf  = h_bf  + (size_t)BL_*D_;
    u16* h2_bf  = yb_bf + (size_t)2*BL_*DI_;
    u16* hid_bf = h2_bf + (size_t)BL_*D_;
    u16* w_in   = hid_bf + (size_t)BL_*FF_;
    u16* w_out  = w_in  + (size_t)2*(2*DI_)*D_;
    u16* w_m1   = w_out + (size_t)2*D_*DI_;
    u16* w_m2   = w_m1  + (size_t)FF_*D_;

    float* ob       = xz;                        // 2*BL*D
    float* part_out = xz + (size_t)2*BL_*D_;     // [2][2][BL*D]
    float* part_m2  = xz;                        // [4][BL*D] (ob dead by then)
    float* y        = dtw;                       // in-place scan output

    for (int i = 0; i < DEPTH_; ++i) {
        // weight conversion (per layer)
        { int n4 = 2*(2*DI_)*D_/4; cvt_bf16<<<(n4+255)/256,256,0,stream>>>(in_w  + (size_t)i*2*(2*DI_)*D_, w_in,  n4); }
        { int n4 = 2*D_*DI_/4;     cvt_bf16<<<(n4+255)/256,256,0,stream>>>(out_w + (size_t)i*2*D_*DI_,     w_out, n4); }
        { int n4 = FF_*D_/4;       cvt_bf16<<<(n4+255)/256,256,0,stream>>>(mlp_w1+ (size_t)i*FF_*D_,       w_m1,  n4); }
        { int n4 = D_*FF_/4;       cvt_bf16<<<(n4+255)/256,256,0,stream>>>(mlp_w2+ (size_t)i*D_*FF_,       w_m2,  n4); }

        const float* xprev = (i==0) ? x_in : (out + OUT_XS + (size_t)(i-1)*BL_*D_);
        ln_res_kernel<<<BL_, 256, 0, stream>>>(xprev, res, h_bf,
            ln1_w + (size_t)i*D_, ln1_b + (size_t)i*D_, (i==0)?0:1);

        // in_proj: xz[z] = h @ in_w[z]^T
        dim3 gIn(BL_/128, (2*DI_)/128, 2);
        gemm_bf16<0,0><<<gIn, 256, 0, stream>>>(h_bf, w_in, xz, nullptr, nullptr,
            BL_, 2*DI_, D_, 1, 0L, (long)(2*DI_)*D_, (long)BL_*2*DI_);

        conv_silu_kernel<<<(2*BL_*DI_+255)/256, 256, 0, stream>>>(xz, conv_w, conv_b, xc, i);

        // xproj (fp32, split-K=8 atomics)
        zero_kernel<<<(2*BL_*80+255)/256, 256, 0, stream>>>(xdbl, 2*BL_*80);
        dim3 gXp(BL_/64, 2, 2*8);
        gemm_nt<<<gXp, 256, 0, stream>>>(xc, xproj_w + (size_t)i*2*80*DI_, xdbl, nullptr,
            BL_, 80, DI_, DI_, DI_, 80,
            (long)BL_*DI_, (long)80*DI_, (long)BL_*80, 0L, 0, 8);

        // dtproj (fp32, softplus)
        dim3 gDt(BL_/64, DI_/64, 2);
        gemm_nt<<<gDt, 256, 0, stream>>>(xdbl, dtproj_w + (size_t)i*2*DI_*R_, dtw,
            dtproj_b + (size_t)i*2*DI_,
            BL_, DI_, R_, 80, R_, DI_,
            (long)BL_*80, (long)DI_*R_, (long)BL_*DI_, (long)DI_, 1, 1);

        scatter_dts<<<(2*BL_*DI_+255)/256, 256, 0, stream>>>(dtw, out, i);
        scatter_dtlr<<<(2*BL_*R_+255)/256, 256, 0, stream>>>(xdbl, out, i);

        // chunked scan
        scan_part<<<2*B_*CH_*NDG_, 256, 0, stream>>>(dtw, xdbl, xc, A_log, hp, Pp, i);
        scan_combine<<<2*B_*NDG_, 256, 0, stream>>>(hp, Pp);
        scan_final<<<2*B_*CH_*NDG_, 256, 0, stream>>>(dtw, xdbl, xc, A_log, hp, y, i);

        gate_kernel<<<(2*BL_*DI_+255)/256, 256, 0, stream>>>(y, xc, xz, D_param, yb_bf, i);

        // out_proj: split-K=2 bf16, partials -> reduce into ob
        dim3 gOut(BL_/128, D_/128, 2*2);
        gemm_bf16<0,0><<<gOut, 256, 0, stream>>>(yb_bf, w_out, part_out, nullptr, nullptr,
            BL_, D_, DI_, 2, (long)BL_*DI_, (long)D_*DI_, (long)BL_*D_);
        dim3 gRo((BL_*D_+255)/256, 2);
        reduce_k<0><<<gRo, 256, 0, stream>>>(part_out, ob, nullptr, BL_*D_, D_, 2);

        merge_ln_kernel<<<BL_, 256, 0, stream>>>(ob, ob + (size_t)BL_*D_, res, h2_bf,
            ln2_w + (size_t)i*D_, ln2_b + (size_t)i*D_);

        // mlp1: bf16, gelu, bf16 out
        dim3 gM1(BL_/128, FF_/128, 1);
        gemm_bf16<2,1><<<gM1, 256, 0, stream>>>(h2_bf, w_m1, nullptr, hid_bf,
            mlp_b1 + (size_t)i*FF_, BL_, FF_, D_, 1, 0L, 0L, 0L);

        // mlp2: split-K=4, partials -> reduce (+bias) into xs output
        dim3 gM2(BL_/128, D_/128, 4);
        gemm_bf16<0,0><<<gM2, 256, 0, stream>>>(hid_bf, w_m2, part_m2, nullptr, nullptr,
            BL_, D_, FF_, 4, 0L, 0L, (long)BL_*D_);
        dim3 gRm((BL_*D_+255)/256, 1);
        reduce_k<3><<<gRm, 256, 0, stream>>>(part_m2, out + OUT_XS + (size_t)i*BL_*D_,
            mlp_b2 + (size_t)i*D_, BL_*D_, D_, 4);
    }

    copy_kernel<<<(BL_*D_+255)/256, 256, 0, stream>>>(
        out + OUT_XS + (size_t)(DEPTH_-1)*BL_*D_, out, BL_*D_);
}

// Round 3
// 1870.037 us; speedup vs baseline: 6.0761x; 1.4858x over previous
//
#include <hip/hip_runtime.h>
#include <cmath>

#define B_ 2
#define L_ 1024
#define D_ 768
#define DEPTH_ 6
#define DI_ 1536
#define NS_ 16
#define KC_ 4
#define R_ 48
#define FF_ 3072
#define BL_ (B_*L_)
#define XD_ 128
#define CH2_ 64
#define S_ 16

#define OUT_XS   ((size_t)BL_*D_)
#define OUT_DTS  (OUT_XS + (size_t)DEPTH_*BL_*D_)
#define OUT_DTLR (OUT_DTS + (size_t)DEPTH_*2*BL_*DI_)

typedef unsigned short u16;
typedef unsigned int u32;
typedef __bf16 bf16x8 __attribute__((ext_vector_type(8)));
typedef float f32x4 __attribute__((ext_vector_type(4)));

__device__ __forceinline__ float siluf(float x){ return x / (1.f + __expf(-x)); }
__device__ __forceinline__ float softplusf(float x){ return fmaxf(x,0.f) + log1pf(__expf(-fabsf(x))); }
__device__ __forceinline__ float geluf(float x){ return 0.5f*x*(1.f+erff(x*0.7071067811865475f)); }
__device__ __forceinline__ u32 f2bf(float f){
    u32 u = __float_as_uint(f);
    return (u + 0x7FFFu + ((u>>16)&1u)) >> 16;
}
__device__ __forceinline__ float bf2f(u16 v){ return __uint_as_float(((u32)v)<<16); }

// ---------------- fp32 -> bf16 conversion (4 elems/thread) ----------------
__global__ __launch_bounds__(256) void cvt_bf16(const float* __restrict__ in,
                                                u16* __restrict__ out, int n4)
{
    int i = blockIdx.x*256 + threadIdx.x;
    if (i >= n4) return;
    float4 v = ((const float4*)in)[i];
    uint2 o;
    o.x = f2bf(v.x) | (f2bf(v.y) << 16);
    o.y = f2bf(v.z) | (f2bf(v.w) << 16);
    ((uint2*)out)[i] = o;
}

// xproj_w [2][80][1536] -> bf16 padded [2][128][1536]
__global__ __launch_bounds__(256) void cvt_xp(const float* __restrict__ src, u16* __restrict__ dst)
{
    int idx = blockIdx.x*256 + threadIdx.x;
    if (idx >= 2*XD_*DI_) return;
    int k = idx % DI_;
    int rr = (idx / DI_) % XD_;
    int z = idx / (DI_*XD_);
    float v = (rr < 80) ? src[((size_t)z*80 + rr)*DI_ + k] : 0.f;
    dst[idx] = (u16)f2bf(v);
}

// dtproj_w [2][1536][48] -> bf16 padded [2][1536][64]
__global__ __launch_bounds__(256) void cvt_wdt(const float* __restrict__ src, u16* __restrict__ dst)
{
    int idx = blockIdx.x*256 + threadIdx.x;
    if (idx >= 2*DI_*64) return;
    int c = idx % 64;
    int r = (idx / 64) % DI_;
    int z = idx / (64*DI_);
    float v = (c < 48) ? src[((size_t)z*DI_ + r)*48 + c] : 0.f;
    dst[idx] = (u16)f2bf(v);
}

// dt_lr: xdbl[...,:48] -> bf16 padded [2][BL][64], + fused flipped dtlr output (fp32)
__global__ __launch_bounds__(256) void cvt_dtlr(const float* __restrict__ xdbl,
                                                u16* __restrict__ dst,
                                                float* __restrict__ out, int layer)
{
    int idx = blockIdx.x*256 + threadIdx.x;
    if (idx >= 2*BL_*64) return;
    int c = idx % 64;
    int bl = (idx / 64) % BL_;
    int dir = idx / (64*BL_);
    float v = (c < 48) ? xdbl[(size_t)dir*BL_*XD_ + (size_t)bl*XD_ + c] : 0.f;
    dst[idx] = (u16)f2bf(v);
    if (c < 48) {
        int b = bl / L_, p = bl % L_;
        int t = dir ? (L_-1-p) : p;
        out[OUT_DTLR + ((((size_t)layer*2+dir)*B_ + b)*L_ + t)*R_ + c] = v;
    }
}

// ---------------- bf16 MFMA GEMM: C[m,n] = sum_k A[m,k]*Bw[n,k] ----------------
// 128x128 tile, BK=64. EPI: 0 none, 2 bias+gelu->bf16, 4 bias+softplus->C + flipped dts
template<int EPI, int OUTBF>
__global__ __launch_bounds__(256) void gemm_bf16(
    const u16* __restrict__ A, const u16* __restrict__ Bw,
    float* __restrict__ C, u16* __restrict__ Cbf, const float* __restrict__ bias,
    float* __restrict__ out2, int layer,
    int M, int N, int K, int KS, long aS, long bS, long cS, long biasS)
{
    const int zAll = blockIdx.z;
    const int sk = zAll % KS, zb = zAll / KS;
    A  += (size_t)zb * aS;
    Bw += (size_t)zb * bS;
    __shared__ u16 As[128*64];
    __shared__ u16 Bs[128*64];
    const int tid = threadIdx.x;
    const int w = tid >> 6, l = tid & 63;
    const int wr = w >> 1, wc = w & 1;
    const int row0 = blockIdx.x * 128, col0 = blockIdx.y * 128;
    const int Ksl = K / KS;
    const int kbeg = sk * Ksl;
    const int srow = l >> 3;
    const int scol = (l & 7) * 8;
    f32x4 acc[4][4] = {};
    for (int k0 = kbeg; k0 < kbeg + Ksl; k0 += 64) {
        #pragma unroll
        for (int c = 0; c < 4; ++c) {
            int chunk = w*4 + c;
            const u16* ga = A + (size_t)(row0 + chunk*8 + srow) * K + (k0 + scol);
            __builtin_amdgcn_global_load_lds(
                (const __attribute__((address_space(1))) void*)ga,
                (__attribute__((address_space(3))) void*)(As + chunk*512), 16, 0, 0);
            const u16* gb = Bw + (size_t)(col0 + chunk*8 + srow) * K + (k0 + scol);
            __builtin_amdgcn_global_load_lds(
                (const __attribute__((address_space(1))) void*)gb,
                (__attribute__((address_space(3))) void*)(Bs + chunk*512), 16, 0, 0);
        }
        __syncthreads();
        #pragma unroll
        for (int kk = 0; kk < 64; kk += 32) {
            bf16x8 af[4], bfr[4];
            #pragma unroll
            for (int m = 0; m < 4; ++m)
                af[m] = *(const bf16x8*)(As + (wr*64 + m*16 + (l&15))*64 + kk + (l>>4)*8);
            #pragma unroll
            for (int n = 0; n < 4; ++n)
                bfr[n] = *(const bf16x8*)(Bs + (wc*64 + n*16 + (l&15))*64 + kk + (l>>4)*8);
            #pragma unroll
            for (int m = 0; m < 4; ++m)
                #pragma unroll
                for (int n = 0; n < 4; ++n)
                    acc[m][n] = __builtin_amdgcn_mfma_f32_16x16x32_bf16(af[m], bfr[n], acc[m][n], 0, 0, 0);
        }
        __syncthreads();
    }
    if (KS > 1) {
        float* Cp = C + (size_t)(zb*KS + sk) * cS;
        #pragma unroll
        for (int m = 0; m < 4; ++m)
            #pragma unroll
            for (int j = 0; j < 4; ++j) {
                int r = row0 + wr*64 + m*16 + (l>>4)*4 + j;
                #pragma unroll
                for (int n = 0; n < 4; ++n) {
                    int col = col0 + wc*64 + n*16 + (l&15);
                    Cp[(size_t)r*N + col] = acc[m][n][j];
                }
            }
    } else {
        #pragma unroll
        for (int m = 0; m < 4; ++m)
            #pragma unroll
            for (int j = 0; j < 4; ++j) {
                int r = row0 + wr*64 + m*16 + (l>>4)*4 + j;
                #pragma unroll
                for (int n = 0; n < 4; ++n) {
                    int col = col0 + wc*64 + n*16 + (l&15);
                    float v = acc[m][n][j];
                    if (EPI == 2) v = geluf(v + bias[col]);
                    else if (EPI == 4) v = softplusf(v + bias[(size_t)zb*biasS + col]);
                    if (EPI == 4) {
                        C[(size_t)zb*cS + (size_t)r*N + col] = v;
                        int b = r / L_, p = r % L_;
                        int t = zb ? (L_-1-p) : p;
                        out2[((((size_t)layer*2+zb)*B_ + b)*L_ + t)*DI_ + col] = v;
                    } else if (OUTBF) {
                        Cbf[(size_t)zb*cS + (size_t)r*N + col] = (u16)f2bf(v);
                    } else {
                        C[(size_t)zb*cS + (size_t)r*N + col] = v;
                    }
                }
            }
    }
}

// ---------------- split-K partial reduce ----------------
__global__ __launch_bounds__(256) void reduce_k(
    const float* __restrict__ part, float* __restrict__ C, int MN, int KS)
{
    int zb = blockIdx.y;
    int idx = blockIdx.x*256 + threadIdx.x;
    if (idx >= MN) return;
    const float* p = part + (size_t)zb*KS*MN;
    float s = 0.f;
    for (int sk = 0; sk < KS; ++sk) s += p[(size_t)sk*MN + idx];
    C[(size_t)zb*MN + idx] = s;
}

// ---------------- prologue: residual = x_in; h = LN1(residual) ----------------
__global__ __launch_bounds__(256) void ln_res_kernel(
    const float* __restrict__ xprev, float* __restrict__ residual,
    u16* __restrict__ hout, const float* __restrict__ w,
    const float* __restrict__ bia)
{
    int row = blockIdx.x; int tid = threadIdx.x;
    __shared__ float sbuf[8];
    float v[3]; float s=0.f, ss=0.f;
    size_t base = (size_t)row*D_;
    #pragma unroll
    for (int j=0;j<3;j++){
        int c = tid + j*256;
        float x = xprev[base+c];
        v[j]=x; s+=x; ss+=x*x;
        residual[base+c] = x;
    }
    for (int off=32; off; off>>=1){ s += __shfl_down(s,off); ss += __shfl_down(ss,off); }
    int wid = tid>>6, lane = tid&63;
    if (lane==0){ sbuf[wid]=s; sbuf[4+wid]=ss; }
    __syncthreads();
    if (tid==0){
        float S=sbuf[0]+sbuf[1]+sbuf[2]+sbuf[3];
        float SS=sbuf[4]+sbuf[5]+sbuf[6]+sbuf[7];
        float mean = S/(float)D_;
        float var = SS/(float)D_ - mean*mean;
        sbuf[0]=mean; sbuf[1]=rsqrtf(var+1e-5f);
    }
    __syncthreads();
    float mean=sbuf[0], inv=sbuf[1];
    #pragma unroll
    for (int j=0;j<3;j++){
        int c = tid + j*256;
        hout[base+c] = (u16)f2bf((v[j]-mean)*inv*w[c]+bia[c]);
    }
}

// ---------------- merge dirs (from out_proj partials) + residual + LN2 -> bf16 h2 ----------------
__global__ __launch_bounds__(256) void merge_ln_kernel(
    const float* __restrict__ part, float* __restrict__ residual,
    u16* __restrict__ h2, const float* __restrict__ w, const float* __restrict__ bia)
{
    int row = blockIdx.x; int tid = threadIdx.x;
    const size_t MN = (size_t)BL_*D_;
    __shared__ float sbuf[8];
    float v[3]; float s=0.f, ss=0.f;
    size_t base = (size_t)row*D_;
    #pragma unroll
    for (int j=0;j<3;j++){
        int c = tid + j*256;
        float o = part[base+c] + part[MN+base+c] + part[2*MN+base+c] + part[3*MN+base+c];
        float x = residual[base+c] + 0.5f*o;
        v[j]=x; s+=x; ss+=x*x;
        residual[base+c] = x;
    }
    for (int off=32; off; off>>=1){ s += __shfl_down(s,off); ss += __shfl_down(ss,off); }
    int wid = tid>>6, lane = tid&63;
    if (lane==0){ sbuf[wid]=s; sbuf[4+wid]=ss; }
    __syncthreads();
    if (tid==0){
        float S=sbuf[0]+sbuf[1]+sbuf[2]+sbuf[3];
        float SS=sbuf[4]+sbuf[5]+sbuf[6]+sbuf[7];
        float mean = S/(float)D_;
        float var = SS/(float)D_ - mean*mean;
        sbuf[0]=mean; sbuf[1]=rsqrtf(var+1e-5f);
    }
    __syncthreads();
    float mean=sbuf[0], inv=sbuf[1];
    #pragma unroll
    for (int j=0;j<3;j++){
        int c = tid + j*256;
        h2[base+c] = (u16)f2bf((v[j]-mean)*inv*w[c]+bia[c]);
    }
}

// ---- mlp2 partial reduce + bias -> xs[i]; residual += x; h = LN1[i+1](residual) ----
__global__ __launch_bounds__(256) void mlp2red_ln(
    const float* __restrict__ part, const float* __restrict__ b2,
    float* __restrict__ xs_out, float* __restrict__ residual,
    u16* __restrict__ hout, const float* __restrict__ w, const float* __restrict__ bia)
{
    int row = blockIdx.x; int tid = threadIdx.x;
    const size_t MN = (size_t)BL_*D_;
    __shared__ float sbuf[8];
    float v[3]; float s=0.f, ss=0.f;
    size_t base = (size_t)row*D_;
    #pragma unroll
    for (int j=0;j<3;j++){
        int c = tid + j*256;
        float x = part[base+c] + part[MN+base+c] + part[2*MN+base+c] + part[3*MN+base+c] + b2[c];
        xs_out[base+c] = x;
        float r = residual[base+c] + x;
        residual[base+c] = r;
        v[j]=r; s+=r; ss+=r*r;
    }
    for (int off=32; off; off>>=1){ s += __shfl_down(s,off); ss += __shfl_down(ss,off); }
    int wid = tid>>6, lane = tid&63;
    if (lane==0){ sbuf[wid]=s; sbuf[4+wid]=ss; }
    __syncthreads();
    if (tid==0){
        float S=sbuf[0]+sbuf[1]+sbuf[2]+sbuf[3];
        float SS=sbuf[4]+sbuf[5]+sbuf[6]+sbuf[7];
        float mean = S/(float)D_;
        float var = SS/(float)D_ - mean*mean;
        sbuf[0]=mean; sbuf[1]=rsqrtf(var+1e-5f);
    }
    __syncthreads();
    float mean=sbuf[0], inv=sbuf[1];
    #pragma unroll
    for (int j=0;j<3;j++){
        int c = tid + j*256;
        hout[base+c] = (u16)f2bf((v[j]-mean)*inv*w[c]+bia[c]);
    }
}

// ---- last layer: reduce + bias -> xs[5] and out[0] ----
__global__ __launch_bounds__(256) void mlp2red_final(
    const float* __restrict__ part, const float* __restrict__ b2,
    float* __restrict__ xs_out, float* __restrict__ out0)
{
    int idx = blockIdx.x*256 + threadIdx.x;
    if (idx >= BL_*D_) return;
    const size_t MN = (size_t)BL_*D_;
    int c = idx % D_;
    float x = part[idx] + part[MN+idx] + part[2*MN+idx] + part[3*MN+idx] + b2[c];
    xs_out[idx] = x;
    out0[idx] = x;
}

// ---------------- depthwise conv + SiLU (bf16 in, bf16 out) ----------------
__global__ __launch_bounds__(256) void conv_silu_kernel(
    const u16* __restrict__ xz, const float* __restrict__ conv_w,
    const float* __restrict__ conv_b, u16* __restrict__ xc, int layer)
{
    int idx = blockIdx.x * 256 + threadIdx.x;
    if (idx >= 2*BL_*DI_) return;
    int d = idx % DI_;
    int bl = (idx / DI_) % BL_;
    int dir = idx / (DI_*BL_);
    int b = bl / L_, p = bl % L_;
    const float* w = conv_w + ((size_t)(layer*2+dir)*DI_ + d)*KC_;
    float acc = conv_b[(size_t)(layer*2+dir)*DI_ + d];
    const u16* xp = xz + (size_t)dir*BL_*2*DI_ + d;
    #pragma unroll
    for (int k = 0; k < KC_; ++k) {
        int q = (dir == 0) ? (p - 3 + k) : (p + 3 - k);
        if (q >= 0 && q < L_)
            acc = fmaf(bf2f(xp[(size_t)(b*L_+q)*2*DI_]), w[k], acc);
    }
    xc[idx] = (u16)f2bf(siluf(acc));
}

// ---------------- chunked scan, thread-per-d with 16 n-states ----------------
// phase 1: per-chunk local h and prod(dA)
__global__ __launch_bounds__(256) void scan_part2(
    const float* __restrict__ dt, const u16* __restrict__ xc,
    const float* __restrict__ xdbl, const float* __restrict__ A_log,
    float* __restrict__ hp, float* __restrict__ Pp, int layer)
{
    int bid = blockIdx.x;
    int dblk = bid % (DI_/256);
    int chunk = (bid/(DI_/256)) % CH2_;
    int b = (bid/((DI_/256)*CH2_)) % B_;
    int dir = bid / ((DI_/256)*CH2_*B_);
    int tid = threadIdx.x;
    int d = dblk*256 + tid;
    __shared__ float sB[S_][16];
    {
        int i = tid;
        if (i < S_*16) {
            int s = i >> 4, n = i & 15;
            int sidx = chunk*S_ + s;
            int p = dir ? (L_-1-sidx) : sidx;
            sB[s][n] = xdbl[(size_t)dir*BL_*XD_ + (size_t)(b*L_+p)*XD_ + 48 + n];
        }
    }
    __syncthreads();
    float Av[16];
    const float* Ap = A_log + (((size_t)layer*2+dir)*DI_ + d)*NS_;
    #pragma unroll
    for (int n = 0; n < 16; ++n) Av[n] = -__expf(Ap[n]);
    float h[16] = {};
    float P[16];
    #pragma unroll
    for (int n = 0; n < 16; ++n) P[n] = 1.f;
    const float* dtp = dt + (size_t)dir*BL_*DI_ + (size_t)b*L_*DI_ + d;
    const u16*  xcp = xc + (size_t)dir*BL_*DI_ + (size_t)b*L_*DI_ + d;
    #pragma unroll 2
    for (int s = 0; s < S_; ++s) {
        int sidx = chunk*S_ + s;
        int p = dir ? (L_-1-sidx) : sidx;
        float dtv = dtp[(size_t)p*DI_];
        float xv  = bf2f(xcp[(size_t)p*DI_]);
        float u = dtv * xv;
        #pragma unroll
        for (int n = 0; n < 16; ++n) {
            float dA = __expf(dtv*Av[n]);
            P[n] *= dA;
            h[n] = fmaf(dA, h[n], u*sB[s][n]);
        }
    }
    size_t o = (((size_t)(dir*B_+b)*CH2_ + chunk)*DI_ + d)*16;
    #pragma unroll
    for (int n = 0; n < 16; n += 4) {
        *(float4*)&hp[o+n] = make_float4(h[n],h[n+1],h[n+2],h[n+3]);
        *(float4*)&Pp[o+n] = make_float4(P[n],P[n+1],P[n+2],P[n+3]);
    }
}

// phase 2: sequential combine over chunks; hp becomes h_init per chunk
__global__ __launch_bounds__(256) void scan_combine(
    float* __restrict__ hp, const float* __restrict__ Pp)
{
    int bid = blockIdx.x;
    int seg = bid % (DI_*16/256);
    int b = (bid/(DI_*16/256)) % B_;
    int dir = bid / ((DI_*16/256)*B_);
    int idx = seg*256 + threadIdx.x;
    size_t base = ((size_t)(dir*B_+b)*CH2_)*DI_*16 + idx;
    float h = 0.f;
    for (int c = 0; c < CH2_; ++c) {
        size_t i = base + (size_t)c*DI_*16;
        float Pv = Pp[i], hl = hp[i];
        hp[i] = h;
        h = fmaf(Pv, h, hl);
    }
}

// phase 3: recompute with h_init, y = C.h, fused gate -> yb bf16
__global__ __launch_bounds__(256) void scan_final2(
    const float* __restrict__ dt, const u16* __restrict__ xc,
    const float* __restrict__ xdbl, const float* __restrict__ A_log,
    const float* __restrict__ hp, const u16* __restrict__ xz,
    const float* __restrict__ Dp, u16* __restrict__ yb, int layer)
{
    int bid = blockIdx.x;
    int dblk = bid % (DI_/256);
    int chunk = (bid/(DI_/256)) % CH2_;
    int b = (bid/((DI_/256)*CH2_)) % B_;
    int dir = bid / ((DI_/256)*CH2_*B_);
    int tid = threadIdx.x;
    int d = dblk*256 + tid;
    __shared__ float sB[S_][16], sC[S_][16];
    {
        int i = tid;
        if (i < S_*16*2) {
            int which = i >= S_*16;
            int j = i & (S_*16-1);
            int s = j >> 4, n = j & 15;
            int sidx = chunk*S_ + s;
            int p = dir ? (L_-1-sidx) : sidx;
            float v = xdbl[(size_t)dir*BL_*XD_ + (size_t)(b*L_+p)*XD_ + (which?64:48) + n];
            if (which) sC[s][n] = v; else sB[s][n] = v;
        }
    }
    __syncthreads();
    float Av[16];
    const float* Ap = A_log + (((size_t)layer*2+dir)*DI_ + d)*NS_;
    #pragma unroll
    for (int n = 0; n < 16; ++n) Av[n] = -__expf(Ap[n]);
    float h[16];
    {
        size_t o = (((size_t)(dir*B_+b)*CH2_ + chunk)*DI_ + d)*16;
        #pragma unroll
        for (int n = 0; n < 16; n += 4) {
            float4 t = *(const float4*)&hp[o+n];
            h[n]=t.x; h[n+1]=t.y; h[n+2]=t.z; h[n+3]=t.w;
        }
    }
    float Dpv = Dp[(size_t)(layer*2+dir)*DI_ + d];
    const float* dtp = dt + (size_t)dir*BL_*DI_ + (size_t)b*L_*DI_ + d;
    const u16*  xcp = xc + (size_t)dir*BL_*DI_ + (size_t)b*L_*DI_ + d;
    const u16*  zp  = xz + (size_t)dir*BL_*2*DI_ + (size_t)b*L_*2*DI_ + DI_ + d;
    u16* yp = yb + (size_t)dir*BL_*DI_ + (size_t)b*L_*DI_ + d;
    #pragma unroll 2
    for (int s = 0; s < S_; ++s) {
        int sidx = chunk*S_ + s;
        int p = dir ? (L_-1-sidx) : sidx;
        float dtv = dtp[(size_t)p*DI_];
        float xv  = bf2f(xcp[(size_t)p*DI_]);
        float u = dtv * xv;
        float y = 0.f;
        #pragma unroll
        for (int n = 0; n < 16; ++n) {
            float dA = __expf(dtv*Av[n]);
            h[n] = fmaf(dA, h[n], u*sB[s][n]);
            y = fmaf(h[n], sC[s][n], y);
        }
        float z = bf2f(zp[(size_t)p*2*DI_]);
        float v = y + xv*Dpv;
        yp[(size_t)p*DI_] = (u16)f2bf(v * siluf(z));
    }
}

extern "C" void kernel_launch(void* const* d_in, const int* in_sizes, int n_in,
                              void* d_out, int out_size, void* d_ws, size_t ws_size,
                              hipStream_t stream)
{
    const float* x_in    = (const float*)d_in[0];
    const float* ln1_w   = (const float*)d_in[1];
    const float* ln1_b   = (const float*)d_in[2];
    const float* ln2_w   = (const float*)d_in[3];
    const float* ln2_b   = (const float*)d_in[4];
    const float* in_w    = (const float*)d_in[5];
    const float* conv_w  = (const float*)d_in[6];
    const float* conv_b  = (const float*)d_in[7];
    const float* xproj_w = (const float*)d_in[8];
    const float* dtproj_w= (const float*)d_in[9];
    const float* dtproj_b= (const float*)d_in[10];
    const float* A_log   = (const float*)d_in[11];
    const float* D_param = (const float*)d_in[12];
    const float* out_w   = (const float*)d_in[13];
    const float* mlp_w1  = (const float*)d_in[14];
    const float* mlp_b1  = (const float*)d_in[15];
    const float* mlp_w2  = (const float*)d_in[16];
    const float* mlp_b2  = (const float*)d_in[17];

    float* out = (float*)d_out;
    char* base = (char*)d_ws;
    float* res    = (float*)base;  base += (size_t)BL_*D_*4;
    u16*   xz     = (u16*)base;    base += (size_t)2*BL_*2*DI_*2;
    u16*   xc_bf  = (u16*)base;    base += (size_t)2*BL_*DI_*2;
    float* xdbl   = (float*)base;  base += (size_t)2*BL_*XD_*4;
    float* dtw    = (float*)base;  base += (size_t)2*BL_*DI_*4;
    u16*   dtlr_bf= (u16*)base;    base += (size_t)2*BL_*64*2;
    float* hp     = (float*)base;  base += (size_t)2*B_*CH2_*DI_*16*4;
    float* part   = (float*)base;  base += (size_t)2*B_*CH2_*DI_*16*4; // shared: Pp / gemm partials
    u16*   yb_bf  = (u16*)base;    base += (size_t)2*BL_*DI_*2;
    u16*   h_bf   = (u16*)base;    base += (size_t)BL_*D_*2;
    u16*   h2_bf  = (u16*)base;    base += (size_t)BL_*D_*2;
    u16*   hid_bf = (u16*)base;    base += (size_t)BL_*FF_*2;
    u16*   w_in   = (u16*)base;    base += (size_t)2*(2*DI_)*D_*2;
    u16*   w_out  = (u16*)base;    base += (size_t)2*D_*DI_*2;
    u16*   w_m1   = (u16*)base;    base += (size_t)FF_*D_*2;
    u16*   w_m2   = (u16*)base;    base += (size_t)D_*FF_*2;
    u16*   w_xp   = (u16*)base;    base += (size_t)2*XD_*DI_*2;
    u16*   w_dt   = (u16*)base;    base += (size_t)2*DI_*64*2;

    float* Pp = part;

    // prologue: residual = x_in, h = LN1[0]
    ln_res_kernel<<<BL_, 256, 0, stream>>>(x_in, res, h_bf, ln1_w, ln1_b);

    for (int i = 0; i < DEPTH_; ++i) {
        { int n4 = 2*(2*DI_)*D_/4; cvt_bf16<<<(n4+255)/256,256,0,stream>>>(in_w  + (size_t)i*2*(2*DI_)*D_, w_in,  n4); }
        { int n4 = 2*D_*DI_/4;     cvt_bf16<<<(n4+255)/256,256,0,stream>>>(out_w + (size_t)i*2*D_*DI_,     w_out, n4); }
        { int n4 = FF_*D_/4;       cvt_bf16<<<(n4+255)/256,256,0,stream>>>(mlp_w1+ (size_t)i*FF_*D_,       w_m1,  n4); }
        { int n4 = D_*FF_/4;       cvt_bf16<<<(n4+255)/256,256,0,stream>>>(mlp_w2+ (size_t)i*D_*FF_,       w_m2,  n4); }
        cvt_xp <<<(2*XD_*DI_+255)/256,256,0,stream>>>(xproj_w + (size_t)i*2*80*DI_, w_xp);
        cvt_wdt<<<(2*DI_*64+255)/256,256,0,stream>>>(dtproj_w + (size_t)i*2*DI_*48, w_dt);

        // in_proj -> xz (bf16)
        dim3 gIn(BL_/128, (2*DI_)/128, 2);
        gemm_bf16<0,1><<<gIn, 256, 0, stream>>>(h_bf, w_in, nullptr, xz, nullptr, nullptr, 0,
            BL_, 2*DI_, D_, 1, 0L, (long)(2*DI_)*D_, (long)BL_*2*DI_, 0L);

        conv_silu_kernel<<<(2*BL_*DI_+255)/256, 256, 0, stream>>>(xz, conv_w, conv_b, xc_bf, i);

        // xproj: bf16, split-K=8 partials -> reduce into xdbl [2][BL][128]
        dim3 gXp(BL_/128, 1, 2*8);
        gemm_bf16<0,0><<<gXp, 256, 0, stream>>>(xc_bf, w_xp, part, nullptr, nullptr, nullptr, 0,
            BL_, XD_, DI_, 8, (long)BL_*DI_, (long)XD_*DI_, (long)BL_*XD_, 0L);
        dim3 gRx((BL_*XD_+255)/256, 2);
        reduce_k<<<gRx, 256, 0, stream>>>(part, xdbl, BL_*XD_, 8);

        // dt_lr: bf16 padded copy + fused flipped output
        cvt_dtlr<<<(2*BL_*64+255)/256, 256, 0, stream>>>(xdbl, dtlr_bf, out, i);

        // dtproj: bf16, softplus, writes dtw + flipped dts output
        dim3 gDt(BL_/128, DI_/128, 2);
        gemm_bf16<4,0><<<gDt, 256, 0, stream>>>(dtlr_bf, w_dt, dtw, nullptr,
            dtproj_b + (size_t)i*2*DI_, out + OUT_DTS, i,
            BL_, DI_, 64, 1, (long)BL_*64, (long)DI_*64, (long)BL_*DI_, (long)DI_);

        // chunked scan (Pp aliases part region)
        scan_part2<<<2*B_*CH2_*(DI_/256), 256, 0, stream>>>(dtw, xc_bf, xdbl, A_log, hp, Pp, i);
        scan_combine<<<2*B_*(DI_*16/256), 256, 0, stream>>>(hp, Pp);
        scan_final2<<<2*B_*CH2_*(DI_/256), 256, 0, stream>>>(dtw, xc_bf, xdbl, A_log, hp,
            xz, D_param, yb_bf, i);

        // out_proj: split-K=2 partials (4 slices) -> merge_ln
        dim3 gOut(BL_/128, D_/128, 2*2);
        gemm_bf16<0,0><<<gOut, 256, 0, stream>>>(yb_bf, w_out, part, nullptr, nullptr, nullptr, 0,
            BL_, D_, DI_, 2, (long)BL_*DI_, (long)D_*DI_, (long)BL_*D_, 0L);
        merge_ln_kernel<<<BL_, 256, 0, stream>>>(part, res, h2_bf,
            ln2_w + (size_t)i*D_, ln2_b + (size_t)i*D_);

        // mlp1: gelu -> bf16 hid
        dim3 gM1(BL_/128, FF_/128, 1);
        gemm_bf16<2,1><<<gM1, 256, 0, stream>>>(h2_bf, w_m1, nullptr, hid_bf,
            mlp_b1 + (size_t)i*FF_, nullptr, 0, BL_, FF_, D_, 1, 0L, 0L, 0L, 0L);

        // mlp2: split-K=4 partials
        dim3 gM2(BL_/128, D_/128, 4);
        gemm_bf16<0,0><<<gM2, 256, 0, stream>>>(hid_bf, w_m2, part, nullptr, nullptr, nullptr, 0,
            BL_, D_, FF_, 4, 0L, 0L, (long)BL_*D_, 0L);

        if (i < DEPTH_-1) {
            mlp2red_ln<<<BL_, 256, 0, stream>>>(part, mlp_b2 + (size_t)i*D_,
                out + OUT_XS + (size_t)i*BL_*D_, res, h_bf,
                ln1_w + (size_t)(i+1)*D_, ln1_b + (size_t)(i+1)*D_);
        } else {
            mlp2red_final<<<(BL_*D_+255)/256, 256, 0, stream>>>(part, mlp_b2 + (size_t)i*D_,
                out + OUT_XS + (size_t)i*BL_*D_, out);
        }
    }
}

// Round 4
// 1780.013 us; speedup vs baseline: 6.3834x; 1.0506x over previous
//
#include <hip/hip_runtime.h>
#include <cmath>

#define B_ 2
#define L_ 1024
#define D_ 768
#define DEPTH_ 6
#define DI_ 1536
#define NS_ 16
#define KC_ 4
#define R_ 48
#define FF_ 3072
#define BL_ (B_*L_)
#define XD_ 128
#define CH2_ 32
#define S_ 32

#define OUT_XS   ((size_t)BL_*D_)
#define OUT_DTS  (OUT_XS + (size_t)DEPTH_*BL_*D_)
#define OUT_DTLR (OUT_DTS + (size_t)DEPTH_*2*BL_*DI_)

typedef unsigned short u16;
typedef unsigned int u32;
typedef __bf16 bf16x8 __attribute__((ext_vector_type(8)));
typedef float f32x4 __attribute__((ext_vector_type(4)));

__device__ __forceinline__ float siluf(float x){ return x / (1.f + __expf(-x)); }
__device__ __forceinline__ float softplusf(float x){ return fmaxf(x,0.f) + log1pf(__expf(-fabsf(x))); }
__device__ __forceinline__ float geluf(float x){ return 0.5f*x*(1.f+erff(x*0.7071067811865475f)); }
__device__ __forceinline__ u32 f2bf(float f){
    u32 u = __float_as_uint(f);
    return (u + 0x7FFFu + ((u>>16)&1u)) >> 16;
}
__device__ __forceinline__ float bf2f(u16 v){ return __uint_as_float(((u32)v)<<16); }

// ---------------- all weight conversions for one layer, one launch ----------------
__device__ __forceinline__ void cvt4(const float* __restrict__ in, u16* __restrict__ out, int i)
{
    float4 v = ((const float4*)in)[i];
    uint2 o;
    o.x = f2bf(v.x) | (f2bf(v.y) << 16);
    o.y = f2bf(v.z) | (f2bf(v.w) << 16);
    ((uint2*)out)[i] = o;
}

__global__ __launch_bounds__(256) void cvt_weights(
    const float* __restrict__ in_w, const float* __restrict__ out_w,
    const float* __restrict__ m1, const float* __restrict__ m2,
    const float* __restrict__ xp, const float* __restrict__ wdt,
    u16* __restrict__ w_in, u16* __restrict__ w_out, u16* __restrict__ w_m1,
    u16* __restrict__ w_m2, u16* __restrict__ w_xp, u16* __restrict__ w_dt)
{
    int seg = blockIdx.y;
    int i = blockIdx.x*256 + threadIdx.x;
    if (seg == 0) { if (i < 2*(2*DI_)*D_/4) cvt4(in_w, w_in, i); }
    else if (seg == 1) { if (i < 2*D_*DI_/4) cvt4(out_w, w_out, i); }
    else if (seg == 2) { if (i < FF_*D_/4) cvt4(m1, w_m1, i); }
    else if (seg == 3) { if (i < D_*FF_/4) cvt4(m2, w_m2, i); }
    else if (seg == 4) {
        if (i < 2*XD_*DI_/4) {
            int base = i*4;
            int k = base % DI_;
            int rr = (base/DI_) % XD_;
            int z = base/(DI_*XD_);
            uint2 o = {0u,0u};
            if (rr < 80) {
                float4 v = *(const float4*)&xp[((size_t)z*80 + rr)*DI_ + k];
                o.x = f2bf(v.x) | (f2bf(v.y) << 16);
                o.y = f2bf(v.z) | (f2bf(v.w) << 16);
            }
            ((uint2*)w_xp)[i] = o;
        }
    } else {
        if (i < 2*DI_*64/4) {
            int base = i*4;
            int c = base % 64;
            int r = (base/64) % DI_;
            int z = base/(64*DI_);
            uint2 o = {0u,0u};
            if (c < 48) {
                float4 v = *(const float4*)&wdt[((size_t)z*DI_ + r)*48 + c];
                o.x = f2bf(v.x) | (f2bf(v.y) << 16);
                o.y = f2bf(v.z) | (f2bf(v.w) << 16);
            }
            ((uint2*)w_dt)[i] = o;
        }
    }
}

// ---------------- bf16 MFMA GEMM: C[m,n] = sum_k A[m,k]*Bw[n,k] ----------------
// 128x128 tile, BK=64. EPI: 0 none, 2 bias+gelu->bf16, 4 bias+softplus-> flipped dts out
template<int EPI, int OUTBF>
__global__ __launch_bounds__(256) void gemm_bf16(
    const u16* __restrict__ A, const u16* __restrict__ Bw,
    float* __restrict__ C, u16* __restrict__ Cbf, const float* __restrict__ bias,
    float* __restrict__ out2, int layer,
    int M, int N, int K, int KS, long aS, long bS, long cS, long biasS)
{
    const int zAll = blockIdx.z;
    const int sk = zAll % KS, zb = zAll / KS;
    A  += (size_t)zb * aS;
    Bw += (size_t)zb * bS;
    __shared__ u16 As[128*64];
    __shared__ u16 Bs[128*64];
    const int tid = threadIdx.x;
    const int w = tid >> 6, l = tid & 63;
    const int wr = w >> 1, wc = w & 1;
    const int row0 = blockIdx.x * 128, col0 = blockIdx.y * 128;
    const int Ksl = K / KS;
    const int kbeg = sk * Ksl;
    const int srow = l >> 3;
    const int scol = (l & 7) * 8;
    f32x4 acc[4][4] = {};
    for (int k0 = kbeg; k0 < kbeg + Ksl; k0 += 64) {
        #pragma unroll
        for (int c = 0; c < 4; ++c) {
            int chunk = w*4 + c;
            const u16* ga = A + (size_t)(row0 + chunk*8 + srow) * K + (k0 + scol);
            __builtin_amdgcn_global_load_lds(
                (const __attribute__((address_space(1))) void*)ga,
                (__attribute__((address_space(3))) void*)(As + chunk*512), 16, 0, 0);
            const u16* gb = Bw + (size_t)(col0 + chunk*8 + srow) * K + (k0 + scol);
            __builtin_amdgcn_global_load_lds(
                (const __attribute__((address_space(1))) void*)gb,
                (__attribute__((address_space(3))) void*)(Bs + chunk*512), 16, 0, 0);
        }
        __syncthreads();
        #pragma unroll
        for (int kk = 0; kk < 64; kk += 32) {
            bf16x8 af[4], bfr[4];
            #pragma unroll
            for (int m = 0; m < 4; ++m)
                af[m] = *(const bf16x8*)(As + (wr*64 + m*16 + (l&15))*64 + kk + (l>>4)*8);
            #pragma unroll
            for (int n = 0; n < 4; ++n)
                bfr[n] = *(const bf16x8*)(Bs + (wc*64 + n*16 + (l&15))*64 + kk + (l>>4)*8);
            #pragma unroll
            for (int m = 0; m < 4; ++m)
                #pragma unroll
                for (int n = 0; n < 4; ++n)
                    acc[m][n] = __builtin_amdgcn_mfma_f32_16x16x32_bf16(af[m], bfr[n], acc[m][n], 0, 0, 0);
        }
        __syncthreads();
    }
    if (KS > 1) {
        float* Cp = C + (size_t)(zb*KS + sk) * cS;
        #pragma unroll
        for (int m = 0; m < 4; ++m)
            #pragma unroll
            for (int j = 0; j < 4; ++j) {
                int r = row0 + wr*64 + m*16 + (l>>4)*4 + j;
                #pragma unroll
                for (int n = 0; n < 4; ++n) {
                    int col = col0 + wc*64 + n*16 + (l&15);
                    Cp[(size_t)r*N + col] = acc[m][n][j];
                }
            }
    } else {
        #pragma unroll
        for (int m = 0; m < 4; ++m)
            #pragma unroll
            for (int j = 0; j < 4; ++j) {
                int r = row0 + wr*64 + m*16 + (l>>4)*4 + j;
                #pragma unroll
                for (int n = 0; n < 4; ++n) {
                    int col = col0 + wc*64 + n*16 + (l&15);
                    float v = acc[m][n][j];
                    if (EPI == 2) {
                        Cbf[(size_t)zb*cS + (size_t)r*N + col] = (u16)f2bf(geluf(v + bias[col]));
                    } else if (EPI == 4) {
                        v = softplusf(v + bias[(size_t)zb*biasS + col]);
                        int b = r / L_, p = r % L_;
                        int t = zb ? (L_-1-p) : p;
                        out2[((((size_t)layer*2+zb)*B_ + b)*L_ + t)*DI_ + col] = v;
                    } else if (OUTBF) {
                        Cbf[(size_t)zb*cS + (size_t)r*N + col] = (u16)f2bf(v);
                    } else {
                        C[(size_t)zb*cS + (size_t)r*N + col] = v;
                    }
                }
            }
    }
}

// ---- xproj split-K reduce + dt_lr bf16 pad + flipped dtlr output, fused ----
__global__ __launch_bounds__(256) void xpred_dtlr(
    const float* __restrict__ part, float* __restrict__ xdbl,
    u16* __restrict__ dtlr_bf, float* __restrict__ out, int layer)
{
    int idx = blockIdx.x*256 + threadIdx.x;
    if (idx >= 2*BL_*XD_) return;
    int c = idx % XD_;
    int bl = (idx/XD_) % BL_;
    int z = idx/(XD_*BL_);
    const float* p8 = part + ((size_t)z*8)*BL_*XD_ + (size_t)bl*XD_ + c;
    float s = 0.f;
    #pragma unroll
    for (int sk = 0; sk < 8; ++sk) s += p8[(size_t)sk*BL_*XD_];
    xdbl[idx] = s;
    if (c < 64) dtlr_bf[((size_t)z*BL_ + bl)*64 + c] = (u16)f2bf(c < 48 ? s : 0.f);
    if (c < 48) {
        int b = bl / L_, p = bl % L_;
        int t = z ? (L_-1-p) : p;
        out[OUT_DTLR + ((((size_t)layer*2+z)*B_ + b)*L_ + t)*R_ + c] = s;
    }
}

// ---------------- prologue: residual = x_in; h = LN1(residual) ----------------
__global__ __launch_bounds__(256) void ln_res_kernel(
    const float* __restrict__ xprev, float* __restrict__ residual,
    u16* __restrict__ hout, const float* __restrict__ w,
    const float* __restrict__ bia)
{
    int row = blockIdx.x; int tid = threadIdx.x;
    __shared__ float sbuf[8];
    float v[3]; float s=0.f, ss=0.f;
    size_t base = (size_t)row*D_;
    #pragma unroll
    for (int j=0;j<3;j++){
        int c = tid + j*256;
        float x = xprev[base+c];
        v[j]=x; s+=x; ss+=x*x;
        residual[base+c] = x;
    }
    for (int off=32; off; off>>=1){ s += __shfl_down(s,off); ss += __shfl_down(ss,off); }
    int wid = tid>>6, lane = tid&63;
    if (lane==0){ sbuf[wid]=s; sbuf[4+wid]=ss; }
    __syncthreads();
    if (tid==0){
        float S=sbuf[0]+sbuf[1]+sbuf[2]+sbuf[3];
        float SS=sbuf[4]+sbuf[5]+sbuf[6]+sbuf[7];
        float mean = S/(float)D_;
        float var = SS/(float)D_ - mean*mean;
        sbuf[0]=mean; sbuf[1]=rsqrtf(var+1e-5f);
    }
    __syncthreads();
    float mean=sbuf[0], inv=sbuf[1];
    #pragma unroll
    for (int j=0;j<3;j++){
        int c = tid + j*256;
        hout[base+c] = (u16)f2bf((v[j]-mean)*inv*w[c]+bia[c]);
    }
}

// ---------------- merge dirs (out_proj partials) + residual + LN2 -> bf16 h2 ----------------
__global__ __launch_bounds__(256) void merge_ln_kernel(
    const float* __restrict__ part, float* __restrict__ residual,
    u16* __restrict__ h2, const float* __restrict__ w, const float* __restrict__ bia)
{
    int row = blockIdx.x; int tid = threadIdx.x;
    const size_t MN = (size_t)BL_*D_;
    __shared__ float sbuf[8];
    float v[3]; float s=0.f, ss=0.f;
    size_t base = (size_t)row*D_;
    #pragma unroll
    for (int j=0;j<3;j++){
        int c = tid + j*256;
        float o = part[base+c] + part[MN+base+c] + part[2*MN+base+c] + part[3*MN+base+c];
        float x = residual[base+c] + 0.5f*o;
        v[j]=x; s+=x; ss+=x*x;
        residual[base+c] = x;
    }
    for (int off=32; off; off>>=1){ s += __shfl_down(s,off); ss += __shfl_down(ss,off); }
    int wid = tid>>6, lane = tid&63;
    if (lane==0){ sbuf[wid]=s; sbuf[4+wid]=ss; }
    __syncthreads();
    if (tid==0){
        float S=sbuf[0]+sbuf[1]+sbuf[2]+sbuf[3];
        float SS=sbuf[4]+sbuf[5]+sbuf[6]+sbuf[7];
        float mean = S/(float)D_;
        float var = SS/(float)D_ - mean*mean;
        sbuf[0]=mean; sbuf[1]=rsqrtf(var+1e-5f);
    }
    __syncthreads();
    float mean=sbuf[0], inv=sbuf[1];
    #pragma unroll
    for (int j=0;j<3;j++){
        int c = tid + j*256;
        h2[base+c] = (u16)f2bf((v[j]-mean)*inv*w[c]+bia[c]);
    }
}

// ---- mlp2 partial reduce + bias -> xs[i]; residual += x; h = LN1[i+1](residual) ----
__global__ __launch_bounds__(256) void mlp2red_ln(
    const float* __restrict__ part, const float* __restrict__ b2,
    float* __restrict__ xs_out, float* __restrict__ residual,
    u16* __restrict__ hout, const float* __restrict__ w, const float* __restrict__ bia)
{
    int row = blockIdx.x; int tid = threadIdx.x;
    const size_t MN = (size_t)BL_*D_;
    __shared__ float sbuf[8];
    float v[3]; float s=0.f, ss=0.f;
    size_t base = (size_t)row*D_;
    #pragma unroll
    for (int j=0;j<3;j++){
        int c = tid + j*256;
        float x = part[base+c] + part[MN+base+c] + part[2*MN+base+c] + part[3*MN+base+c] + b2[c];
        xs_out[base+c] = x;
        float r = residual[base+c] + x;
        residual[base+c] = r;
        v[j]=r; s+=r; ss+=r*r;
    }
    for (int off=32; off; off>>=1){ s += __shfl_down(s,off); ss += __shfl_down(ss,off); }
    int wid = tid>>6, lane = tid&63;
    if (lane==0){ sbuf[wid]=s; sbuf[4+wid]=ss; }
    __syncthreads();
    if (tid==0){
        float S=sbuf[0]+sbuf[1]+sbuf[2]+sbuf[3];
        float SS=sbuf[4]+sbuf[5]+sbuf[6]+sbuf[7];
        float mean = S/(float)D_;
        float var = SS/(float)D_ - mean*mean;
        sbuf[0]=mean; sbuf[1]=rsqrtf(var+1e-5f);
    }
    __syncthreads();
    float mean=sbuf[0], inv=sbuf[1];
    #pragma unroll
    for (int j=0;j<3;j++){
        int c = tid + j*256;
        hout[base+c] = (u16)f2bf((v[j]-mean)*inv*w[c]+bia[c]);
    }
}

// ---- last layer: reduce + bias -> xs[5] and out[0] ----
__global__ __launch_bounds__(256) void mlp2red_final(
    const float* __restrict__ part, const float* __restrict__ b2,
    float* __restrict__ xs_out, float* __restrict__ out0)
{
    int idx = blockIdx.x*256 + threadIdx.x;
    if (idx >= BL_*D_) return;
    const size_t MN = (size_t)BL_*D_;
    int c = idx % D_;
    float x = part[idx] + part[MN+idx] + part[2*MN+idx] + part[3*MN+idx] + b2[c];
    xs_out[idx] = x;
    out0[idx] = x;
}

// ---------------- depthwise conv + SiLU, vectorized bf16x8 ----------------
__global__ __launch_bounds__(256) void conv_silu_v(
    const u16* __restrict__ xz, const float* __restrict__ conv_w,
    const float* __restrict__ conv_b, u16* __restrict__ xc, int layer)
{
    const int NG = DI_/8;
    int idx = blockIdx.x*256 + threadIdx.x;
    if (idx >= 2*BL_*NG) return;
    int g = idx % NG;
    int bl = (idx / NG) % BL_;
    int dir = idx / (NG*BL_);
    int b = bl / L_, p = bl % L_;
    int d0 = g*8;
    const float* wp = conv_w + ((size_t)(layer*2+dir)*DI_ + d0)*KC_;
    float w[8][4];
    #pragma unroll
    for (int d = 0; d < 8; ++d) {
        float4 t = ((const float4*)wp)[d];
        w[d][0]=t.x; w[d][1]=t.y; w[d][2]=t.z; w[d][3]=t.w;
    }
    float acc[8];
    const float* bp = conv_b + (size_t)(layer*2+dir)*DI_ + d0;
    #pragma unroll
    for (int d = 0; d < 8; ++d) acc[d] = bp[d];
    const u16* xp = xz + (size_t)dir*BL_*2*DI_ + d0;
    #pragma unroll
    for (int k = 0; k < KC_; ++k) {
        int q = (dir == 0) ? (p - 3 + k) : (p + 3 - k);
        if (q < 0 || q >= L_) continue;
        uint4 raw = *(const uint4*)(xp + (size_t)(b*L_+q)*2*DI_);
        const u16* xv = (const u16*)&raw;
        #pragma unroll
        for (int d = 0; d < 8; ++d) acc[d] = fmaf(bf2f(xv[d]), w[d][k], acc[d]);
    }
    u16 o[8];
    #pragma unroll
    for (int d = 0; d < 8; ++d) o[d] = (u16)f2bf(siluf(acc[d]));
    *(uint4*)(xc + (size_t)dir*BL_*DI_ + (size_t)bl*DI_ + d0) = *(uint4*)o;
}

// ---------------- chunked scan, thread-per-d with 16 n-states ----------------
// dt is read from the dts OUTPUT (both dirs stored in scan order -> row sidx)
__global__ __launch_bounds__(256) void scan_part2(
    const float* __restrict__ dts, const u16* __restrict__ xc,
    const float* __restrict__ xdbl, const float* __restrict__ A_log,
    float* __restrict__ hp, float* __restrict__ Pp, int layer)
{
    int bid = blockIdx.x;
    int dblk = bid % (DI_/256);
    int chunk = (bid/(DI_/256)) % CH2_;
    int b = (bid/((DI_/256)*CH2_)) % B_;
    int dir = bid / ((DI_/256)*CH2_*B_);
    int tid = threadIdx.x;
    int d = dblk*256 + tid;
    __shared__ float sB[S_][16];
    for (int i = tid; i < S_*16; i += 256) {
        int s = i >> 4, n = i & 15;
        int sidx = chunk*S_ + s;
        int p = dir ? (L_-1-sidx) : sidx;
        sB[s][n] = xdbl[(size_t)dir*BL_*XD_ + (size_t)(b*L_+p)*XD_ + 48 + n];
    }
    __syncthreads();
    float Av[16];
    const float* Ap = A_log + (((size_t)layer*2+dir)*DI_ + d)*NS_;
    #pragma unroll
    for (int n = 0; n < 16; ++n) Av[n] = -__expf(Ap[n]);
    float h[16] = {};
    float P[16];
    #pragma unroll
    for (int n = 0; n < 16; ++n) P[n] = 1.f;
    const float* dtp = dts + ((((size_t)layer*2+dir)*B_ + b)*L_)*DI_ + d;
    const u16*  xcp = xc + (size_t)dir*BL_*DI_ + (size_t)b*L_*DI_ + d;
    #pragma unroll 2
    for (int s = 0; s < S_; ++s) {
        int sidx = chunk*S_ + s;
        int p = dir ? (L_-1-sidx) : sidx;
        float dtv = dtp[(size_t)sidx*DI_];
        float xv  = bf2f(xcp[(size_t)p*DI_]);
        float u = dtv * xv;
        #pragma unroll
        for (int n = 0; n < 16; ++n) {
            float dA = __expf(dtv*Av[n]);
            P[n] *= dA;
            h[n] = fmaf(dA, h[n], u*sB[s][n]);
        }
    }
    size_t o = (((size_t)(dir*B_+b)*CH2_ + chunk)*DI_ + d)*16;
    #pragma unroll
    for (int n = 0; n < 16; n += 4) {
        *(float4*)&hp[o+n] = make_float4(h[n],h[n+1],h[n+2],h[n+3]);
        *(float4*)&Pp[o+n] = make_float4(P[n],P[n+1],P[n+2],P[n+3]);
    }
}

// phase 2: sequential combine over chunks; hp becomes h_init per chunk
__global__ __launch_bounds__(256) void scan_combine(
    float* __restrict__ hp, const float* __restrict__ Pp)
{
    int bid = blockIdx.x;
    int seg = bid % (DI_*16/256);
    int b = (bid/(DI_*16/256)) % B_;
    int dir = bid / ((DI_*16/256)*B_);
    int idx = seg*256 + threadIdx.x;
    size_t base = ((size_t)(dir*B_+b)*CH2_)*DI_*16 + idx;
    float h = 0.f;
    for (int c = 0; c < CH2_; ++c) {
        size_t i = base + (size_t)c*DI_*16;
        float Pv = Pp[i], hl = hp[i];
        hp[i] = h;
        h = fmaf(Pv, h, hl);
    }
}

// phase 3: recompute with h_init, y = C.h, fused gate -> yb bf16
__global__ __launch_bounds__(256) void scan_final2(
    const float* __restrict__ dts, const u16* __restrict__ xc,
    const float* __restrict__ xdbl, const float* __restrict__ A_log,
    const float* __restrict__ hp, const u16* __restrict__ xz,
    const float* __restrict__ Dp, u16* __restrict__ yb, int layer)
{
    int bid = blockIdx.x;
    int dblk = bid % (DI_/256);
    int chunk = (bid/(DI_/256)) % CH2_;
    int b = (bid/((DI_/256)*CH2_)) % B_;
    int dir = bid / ((DI_/256)*CH2_*B_);
    int tid = threadIdx.x;
    int d = dblk*256 + tid;
    __shared__ float sB[S_][16], sC[S_][16];
    for (int i = tid; i < S_*16*2; i += 256) {
        int which = i >= S_*16;
        int j = i & (S_*16-1);
        int s = j >> 4, n = j & 15;
        int sidx = chunk*S_ + s;
        int p = dir ? (L_-1-sidx) : sidx;
        float v = xdbl[(size_t)dir*BL_*XD_ + (size_t)(b*L_+p)*XD_ + (which?64:48) + n];
        if (which) sC[s][n] = v; else sB[s][n] = v;
    }
    __syncthreads();
    float Av[16];
    const float* Ap = A_log + (((size_t)layer*2+dir)*DI_ + d)*NS_;
    #pragma unroll
    for (int n = 0; n < 16; ++n) Av[n] = -__expf(Ap[n]);
    float h[16];
    {
        size_t o = (((size_t)(dir*B_+b)*CH2_ + chunk)*DI_ + d)*16;
        #pragma unroll
        for (int n = 0; n < 16; n += 4) {
            float4 t = *(const float4*)&hp[o+n];
            h[n]=t.x; h[n+1]=t.y; h[n+2]=t.z; h[n+3]=t.w;
        }
    }
    float Dpv = Dp[(size_t)(layer*2+dir)*DI_ + d];
    const float* dtp = dts + ((((size_t)layer*2+dir)*B_ + b)*L_)*DI_ + d;
    const u16*  xcp = xc + (size_t)dir*BL_*DI_ + (size_t)b*L_*DI_ + d;
    const u16*  zp  = xz + (size_t)dir*BL_*2*DI_ + (size_t)b*L_*2*DI_ + DI_ + d;
    u16* yp = yb + (size_t)dir*BL_*DI_ + (size_t)b*L_*DI_ + d;
    #pragma unroll 2
    for (int s = 0; s < S_; ++s) {
        int sidx = chunk*S_ + s;
        int p = dir ? (L_-1-sidx) : sidx;
        float dtv = dtp[(size_t)sidx*DI_];
        float xv  = bf2f(xcp[(size_t)p*DI_]);
        float u = dtv * xv;
        float y = 0.f;
        #pragma unroll
        for (int n = 0; n < 16; ++n) {
            float dA = __expf(dtv*Av[n]);
            h[n] = fmaf(dA, h[n], u*sB[s][n]);
            y = fmaf(h[n], sC[s][n], y);
        }
        float z = bf2f(zp[(size_t)p*2*DI_]);
        float v = y + xv*Dpv;
        yp[(size_t)p*DI_] = (u16)f2bf(v * siluf(z));
    }
}

extern "C" void kernel_launch(void* const* d_in, const int* in_sizes, int n_in,
                              void* d_out, int out_size, void* d_ws, size_t ws_size,
                              hipStream_t stream)
{
    const float* x_in    = (const float*)d_in[0];
    const float* ln1_w   = (const float*)d_in[1];
    const float* ln1_b   = (const float*)d_in[2];
    const float* ln2_w   = (const float*)d_in[3];
    const float* ln2_b   = (const float*)d_in[4];
    const float* in_w    = (const float*)d_in[5];
    const float* conv_w  = (const float*)d_in[6];
    const float* conv_b  = (const float*)d_in[7];
    const float* xproj_w = (const float*)d_in[8];
    const float* dtproj_w= (const float*)d_in[9];
    const float* dtproj_b= (const float*)d_in[10];
    const float* A_log   = (const float*)d_in[11];
    const float* D_param = (const float*)d_in[12];
    const float* out_w   = (const float*)d_in[13];
    const float* mlp_w1  = (const float*)d_in[14];
    const float* mlp_b1  = (const float*)d_in[15];
    const float* mlp_w2  = (const float*)d_in[16];
    const float* mlp_b2  = (const float*)d_in[17];

    float* out = (float*)d_out;
    char* base = (char*)d_ws;
    float* res    = (float*)base;  base += (size_t)BL_*D_*4;
    u16*   xz     = (u16*)base;    base += (size_t)2*BL_*2*DI_*2;
    u16*   xc_bf  = (u16*)base;    base += (size_t)2*BL_*DI_*2;
    float* xdbl   = (float*)base;  base += (size_t)2*BL_*XD_*4;
    u16*   dtlr_bf= (u16*)base;    base += (size_t)2*BL_*64*2;
    float* hp     = (float*)base;  base += (size_t)2*B_*CH2_*DI_*16*4;
    float* part   = (float*)base;  base += (size_t)4*BL_*D_*4;   // max: 4 slices of BL*D (also Pp, xproj 16x BL*XD)
    u16*   yb_bf  = (u16*)base;    base += (size_t)2*BL_*DI_*2;
    u16*   h_bf   = (u16*)base;    base += (size_t)BL_*D_*2;
    u16*   h2_bf  = (u16*)base;    base += (size_t)BL_*D_*2;
    u16*   hid_bf = (u16*)base;    base += (size_t)BL_*FF_*2;
    u16*   w_in   = (u16*)base;    base += (size_t)2*(2*DI_)*D_*2;
    u16*   w_out  = (u16*)base;    base += (size_t)2*D_*DI_*2;
    u16*   w_m1   = (u16*)base;    base += (size_t)FF_*D_*2;
    u16*   w_m2   = (u16*)base;    base += (size_t)D_*FF_*2;
    u16*   w_xp   = (u16*)base;    base += (size_t)2*XD_*DI_*2;
    u16*   w_dt   = (u16*)base;    base += (size_t)2*DI_*64*2;

    float* Pp = part;
    float* dts_base = out + OUT_DTS;

    // prologue: residual = x_in, h = LN1[0]
    ln_res_kernel<<<BL_, 256, 0, stream>>>(x_in, res, h_bf, ln1_w, ln1_b);

    for (int i = 0; i < DEPTH_; ++i) {
        cvt_weights<<<dim3(4608, 6), 256, 0, stream>>>(
            in_w  + (size_t)i*2*(2*DI_)*D_, out_w + (size_t)i*2*D_*DI_,
            mlp_w1+ (size_t)i*FF_*D_,       mlp_w2+ (size_t)i*D_*FF_,
            xproj_w + (size_t)i*2*80*DI_,   dtproj_w + (size_t)i*2*DI_*48,
            w_in, w_out, w_m1, w_m2, w_xp, w_dt);

        // in_proj -> xz (bf16)
        dim3 gIn(BL_/128, (2*DI_)/128, 2);
        gemm_bf16<0,1><<<gIn, 256, 0, stream>>>(h_bf, w_in, nullptr, xz, nullptr, nullptr, 0,
            BL_, 2*DI_, D_, 1, 0L, (long)(2*DI_)*D_, (long)BL_*2*DI_, 0L);

        conv_silu_v<<<(2*BL_*(DI_/8)+255)/256, 256, 0, stream>>>(xz, conv_w, conv_b, xc_bf, i);

        // xproj: bf16, split-K=8 partials -> fused reduce + dtlr
        dim3 gXp(BL_/128, 1, 2*8);
        gemm_bf16<0,0><<<gXp, 256, 0, stream>>>(xc_bf, w_xp, part, nullptr, nullptr, nullptr, 0,
            BL_, XD_, DI_, 8, (long)BL_*DI_, (long)XD_*DI_, (long)BL_*XD_, 0L);
        xpred_dtlr<<<(2*BL_*XD_+255)/256, 256, 0, stream>>>(part, xdbl, dtlr_bf, out, i);

        // dtproj: bf16, softplus -> flipped dts output (scan reads from there)
        dim3 gDt(BL_/128, DI_/128, 2);
        gemm_bf16<4,0><<<gDt, 256, 0, stream>>>(dtlr_bf, w_dt, nullptr, nullptr,
            dtproj_b + (size_t)i*2*DI_, dts_base, i,
            BL_, DI_, 64, 1, (long)BL_*64, (long)DI_*64, 0L, (long)DI_);

        // chunked scan (Pp aliases part region)
        scan_part2<<<2*B_*CH2_*(DI_/256), 256, 0, stream>>>(dts_base, xc_bf, xdbl, A_log, hp, Pp, i);
        scan_combine<<<2*B_*(DI_*16/256), 256, 0, stream>>>(hp, Pp);
        scan_final2<<<2*B_*CH2_*(DI_/256), 256, 0, stream>>>(dts_base, xc_bf, xdbl, A_log, hp,
            xz, D_param, yb_bf, i);

        // out_proj: split-K=2 partials (4 slices) -> merge_ln
        dim3 gOut(BL_/128, D_/128, 2*2);
        gemm_bf16<0,0><<<gOut, 256, 0, stream>>>(yb_bf, w_out, part, nullptr, nullptr, nullptr, 0,
            BL_, D_, DI_, 2, (long)BL_*DI_, (long)D_*DI_, (long)BL_*D_, 0L);
        merge_ln_kernel<<<BL_, 256, 0, stream>>>(part, res, h2_bf,
            ln2_w + (size_t)i*D_, ln2_b + (size_t)i*D_);

        // mlp1: gelu -> bf16 hid
        dim3 gM1(BL_/128, FF_/128, 1);
        gemm_bf16<2,1><<<gM1, 256, 0, stream>>>(h2_bf, w_m1, nullptr, hid_bf,
            mlp_b1 + (size_t)i*FF_, nullptr, 0, BL_, FF_, D_, 1, 0L, 0L, (long)BL_*FF_, 0L);

        // mlp2: split-K=4 partials
        dim3 gM2(BL_/128, D_/128, 4);
        gemm_bf16<0,0><<<gM2, 256, 0, stream>>>(hid_bf, w_m2, part, nullptr, nullptr, nullptr, 0,
            BL_, D_, FF_, 4, 0L, 0L, (long)BL_*D_, 0L);

        if (i < DEPTH_-1) {
            mlp2red_ln<<<BL_, 256, 0, stream>>>(part, mlp_b2 + (size_t)i*D_,
                out + OUT_XS + (size_t)i*BL_*D_, res, h_bf,
                ln1_w + (size_t)(i+1)*D_, ln1_b + (size_t)(i+1)*D_);
        } else {
            mlp2red_final<<<(BL_*D_+255)/256, 256, 0, stream>>>(part, mlp_b2 + (size_t)i*D_,
                out + OUT_XS + (size_t)i*BL_*D_, out);
        }
    }
}

// Round 5
// 1653.566 us; speedup vs baseline: 6.8715x; 1.0765x over previous
//
#include <hip/hip_runtime.h>
#include <cmath>

#define B_ 2
#define L_ 1024
#define D_ 768
#define DEPTH_ 6
#define DI_ 1536
#define NS_ 16
#define KC_ 4
#define R_ 48
#define FF_ 3072
#define BL_ (B_*L_)
#define XD_ 128
#define CH2_ 32
#define S_ 32
#define NXZ_ (2*2*DI_)   // 6144: in_proj folded N

#define OUT_XS   ((size_t)BL_*D_)
#define OUT_DTS  (OUT_XS + (size_t)DEPTH_*BL_*D_)
#define OUT_DTLR (OUT_DTS + (size_t)DEPTH_*2*BL_*DI_)

typedef unsigned short u16;
typedef unsigned int u32;
typedef __bf16 bf16x8 __attribute__((ext_vector_type(8)));
typedef float f32x4 __attribute__((ext_vector_type(4)));

__device__ __forceinline__ float siluf(float x){ return x / (1.f + __expf(-x)); }
__device__ __forceinline__ float softplusf(float x){ return fmaxf(x,0.f) + log1pf(__expf(-fabsf(x))); }
__device__ __forceinline__ float geluf(float x){ return 0.5f*x*(1.f+erff(x*0.7071067811865475f)); }
__device__ __forceinline__ u32 f2bf(float f){
    u32 u = __float_as_uint(f);
    return (u + 0x7FFFu + ((u>>16)&1u)) >> 16;
}
__device__ __forceinline__ float bf2f(u16 v){ return __uint_as_float(((u32)v)<<16); }

// ---------------- all weight conversions for one layer, one launch ----------------
__device__ __forceinline__ void cvt4(const float* __restrict__ in, u16* __restrict__ out, int i)
{
    float4 v = ((const float4*)in)[i];
    uint2 o;
    o.x = f2bf(v.x) | (f2bf(v.y) << 16);
    o.y = f2bf(v.z) | (f2bf(v.w) << 16);
    ((uint2*)out)[i] = o;
}

__global__ __launch_bounds__(256) void cvt_weights(
    const float* __restrict__ in_w, const float* __restrict__ out_w,
    const float* __restrict__ m1, const float* __restrict__ m2,
    const float* __restrict__ xp, const float* __restrict__ wdt,
    u16* __restrict__ w_in, u16* __restrict__ w_out, u16* __restrict__ w_m1,
    u16* __restrict__ w_m2, u16* __restrict__ w_xp, u16* __restrict__ w_dt)
{
    int seg = blockIdx.y;
    int i = blockIdx.x*256 + threadIdx.x;
    if (seg == 0) { if (i < 2*(2*DI_)*D_/4) cvt4(in_w, w_in, i); }
    else if (seg == 1) { if (i < 2*D_*DI_/4) cvt4(out_w, w_out, i); }
    else if (seg == 2) { if (i < FF_*D_/4) cvt4(m1, w_m1, i); }
    else if (seg == 3) { if (i < D_*FF_/4) cvt4(m2, w_m2, i); }
    else if (seg == 4) {
        if (i < 2*XD_*DI_/4) {
            int base = i*4;
            int k = base % DI_;
            int rr = (base/DI_) % XD_;
            int z = base/(DI_*XD_);
            uint2 o = {0u,0u};
            if (rr < 80) {
                float4 v = *(const float4*)&xp[((size_t)z*80 + rr)*DI_ + k];
                o.x = f2bf(v.x) | (f2bf(v.y) << 16);
                o.y = f2bf(v.z) | (f2bf(v.w) << 16);
            }
            ((uint2*)w_xp)[i] = o;
        }
    } else {
        if (i < 2*DI_*64/4) {
            int base = i*4;
            int c = base % 64;
            int r = (base/64) % DI_;
            int z = base/(64*DI_);
            uint2 o = {0u,0u};
            if (c < 48) {
                float4 v = *(const float4*)&wdt[((size_t)z*DI_ + r)*48 + c];
                o.x = f2bf(v.x) | (f2bf(v.y) << 16);
                o.y = f2bf(v.z) | (f2bf(v.w) << 16);
            }
            ((uint2*)w_dt)[i] = o;
        }
    }
}

// ---------------- bf16 MFMA GEMM, 128x128 tile, BK=64 ----------------
// Double-buffered LDS + prefetch-before-compute + XOR chunk swizzle (both sides)
// + setprio around MFMA. EPI: 0 none, 2 bias+gelu->bf16, 4 bias+softplus->flipped dts
__device__ __forceinline__ void stage_tile(
    const u16* __restrict__ G, u16* lds, int row0, int ldK, int k0, int w, int l)
{
    const int sub = l >> 3;             // row within 8-row chunk
    const int cg  = (l & 7) ^ sub;      // swizzled source chunk
    #pragma unroll
    for (int c = 0; c < 4; ++c) {
        int chunk = w*4 + c;
        const u16* g = G + (size_t)(row0 + chunk*8 + sub) * ldK + k0 + cg*8;
        __builtin_amdgcn_global_load_lds(
            (const __attribute__((address_space(1))) void*)g,
            (__attribute__((address_space(3))) void*)(lds + chunk*512), 16, 0, 0);
    }
}

__device__ __forceinline__ bf16x8 ldfrag(const u16* lds, int row, int kk2, int l)
{
    int chunk = (kk2*4 + (l>>4)) ^ (l & 7);
    return *(const bf16x8*)(lds + row*64 + chunk*8);
}

template<int EPI, int OUTBF>
__global__ __launch_bounds__(256) void gemm_bf16(
    const u16* __restrict__ A, const u16* __restrict__ Bw,
    float* __restrict__ C, u16* __restrict__ Cbf, const float* __restrict__ bias,
    float* __restrict__ out2, int layer,
    int M, int N, int K, int KS, long aS, long bS, long cS, long biasS)
{
    const int zAll = blockIdx.z;
    const int sk = zAll % KS, zb = zAll / KS;
    A  += (size_t)zb * aS;
    Bw += (size_t)zb * bS;
    __shared__ u16 As[2*128*64];
    __shared__ u16 Bs[2*128*64];
    const int tid = threadIdx.x;
    const int w = tid >> 6, l = tid & 63;
    const int wr = w >> 1, wc = w & 1;
    const int row0 = blockIdx.x * 128, col0 = blockIdx.y * 128;
    const int Ksl = K / KS;
    const int kbeg = sk * Ksl;
    const int nt = Ksl / 64;
    f32x4 acc[4][4] = {};

    stage_tile(A, As, row0, K, kbeg, w, l);
    stage_tile(Bw, Bs, col0, K, kbeg, w, l);
    __syncthreads();

    for (int t = 0; t < nt; ++t) {
        const int cur = t & 1;
        if (t + 1 < nt) {
            stage_tile(A, As + (cur^1)*8192, row0, K, kbeg + (t+1)*64, w, l);
            stage_tile(Bw, Bs + (cur^1)*8192, col0, K, kbeg + (t+1)*64, w, l);
        }
        const u16* Ab = As + cur*8192;
        const u16* Bb = Bs + cur*8192;
        bf16x8 bfr[4][2];
        #pragma unroll
        for (int n = 0; n < 4; ++n)
            #pragma unroll
            for (int kk2 = 0; kk2 < 2; ++kk2)
                bfr[n][kk2] = ldfrag(Bb, wc*64 + n*16 + (l&15), kk2, l);
        #pragma unroll
        for (int m = 0; m < 4; ++m) {
            bf16x8 a0 = ldfrag(Ab, wr*64 + m*16 + (l&15), 0, l);
            bf16x8 a1 = ldfrag(Ab, wr*64 + m*16 + (l&15), 1, l);
            __builtin_amdgcn_s_setprio(1);
            #pragma unroll
            for (int n = 0; n < 4; ++n) {
                acc[m][n] = __builtin_amdgcn_mfma_f32_16x16x32_bf16(a0, bfr[n][0], acc[m][n], 0, 0, 0);
                acc[m][n] = __builtin_amdgcn_mfma_f32_16x16x32_bf16(a1, bfr[n][1], acc[m][n], 0, 0, 0);
            }
            __builtin_amdgcn_s_setprio(0);
        }
        __syncthreads();   // drains vmcnt(0) (prefetch landed) + barrier
    }

    if (KS > 1) {
        float* Cp = C + (size_t)(zb*KS + sk) * cS;
        #pragma unroll
        for (int m = 0; m < 4; ++m)
            #pragma unroll
            for (int j = 0; j < 4; ++j) {
                int r = row0 + wr*64 + m*16 + (l>>4)*4 + j;
                #pragma unroll
                for (int n = 0; n < 4; ++n) {
                    int col = col0 + wc*64 + n*16 + (l&15);
                    Cp[(size_t)r*N + col] = acc[m][n][j];
                }
            }
    } else {
        #pragma unroll
        for (int m = 0; m < 4; ++m)
            #pragma unroll
            for (int j = 0; j < 4; ++j) {
                int r = row0 + wr*64 + m*16 + (l>>4)*4 + j;
                #pragma unroll
                for (int n = 0; n < 4; ++n) {
                    int col = col0 + wc*64 + n*16 + (l&15);
                    float v = acc[m][n][j];
                    if (EPI == 2) {
                        Cbf[(size_t)zb*cS + (size_t)r*N + col] = (u16)f2bf(geluf(v + bias[col]));
                    } else if (EPI == 4) {
                        v = softplusf(v + bias[(size_t)zb*biasS + col]);
                        int b = r / L_, p = r % L_;
                        int tt = zb ? (L_-1-p) : p;
                        out2[((((size_t)layer*2+zb)*B_ + b)*L_ + tt)*DI_ + col] = v;
                    } else if (OUTBF) {
                        Cbf[(size_t)zb*cS + (size_t)r*N + col] = (u16)f2bf(v);
                    } else {
                        C[(size_t)zb*cS + (size_t)r*N + col] = v;
                    }
                }
            }
    }
}

// ---- xproj split-K reduce + dt_lr bf16 pad + flipped dtlr output, fused ----
__global__ __launch_bounds__(256) void xpred_dtlr(
    const float* __restrict__ part, float* __restrict__ xdbl,
    u16* __restrict__ dtlr_bf, float* __restrict__ out, int layer)
{
    int idx = blockIdx.x*256 + threadIdx.x;
    if (idx >= 2*BL_*XD_) return;
    int c = idx % XD_;
    int bl = (idx/XD_) % BL_;
    int z = idx/(XD_*BL_);
    const float* p8 = part + ((size_t)z*8)*BL_*XD_ + (size_t)bl*XD_ + c;
    float s = 0.f;
    #pragma unroll
    for (int sk = 0; sk < 8; ++sk) s += p8[(size_t)sk*BL_*XD_];
    xdbl[idx] = s;
    if (c < 64) dtlr_bf[((size_t)z*BL_ + bl)*64 + c] = (u16)f2bf(c < 48 ? s : 0.f);
    if (c < 48) {
        int b = bl / L_, p = bl % L_;
        int t = z ? (L_-1-p) : p;
        out[OUT_DTLR + ((((size_t)layer*2+z)*B_ + b)*L_ + t)*R_ + c] = s;
    }
}

// ---------------- prologue: residual = x_in; h = LN1(residual) ----------------
__global__ __launch_bounds__(256) void ln_res_kernel(
    const float* __restrict__ xprev, float* __restrict__ residual,
    u16* __restrict__ hout, const float* __restrict__ w,
    const float* __restrict__ bia)
{
    int row = blockIdx.x; int tid = threadIdx.x;
    __shared__ float sbuf[8];
    float v[3]; float s=0.f, ss=0.f;
    size_t base = (size_t)row*D_;
    #pragma unroll
    for (int j=0;j<3;j++){
        int c = tid + j*256;
        float x = xprev[base+c];
        v[j]=x; s+=x; ss+=x*x;
        residual[base+c] = x;
    }
    for (int off=32; off; off>>=1){ s += __shfl_down(s,off); ss += __shfl_down(ss,off); }
    int wid = tid>>6, lane = tid&63;
    if (lane==0){ sbuf[wid]=s; sbuf[4+wid]=ss; }
    __syncthreads();
    if (tid==0){
        float S=sbuf[0]+sbuf[1]+sbuf[2]+sbuf[3];
        float SS=sbuf[4]+sbuf[5]+sbuf[6]+sbuf[7];
        float mean = S/(float)D_;
        float var = SS/(float)D_ - mean*mean;
        sbuf[0]=mean; sbuf[1]=rsqrtf(var+1e-5f);
    }
    __syncthreads();
    float mean=sbuf[0], inv=sbuf[1];
    #pragma unroll
    for (int j=0;j<3;j++){
        int c = tid + j*256;
        hout[base+c] = (u16)f2bf((v[j]-mean)*inv*w[c]+bia[c]);
    }
}

// ---------------- merge dirs (out_proj partials) + residual + LN2 -> bf16 h2 ----------------
__global__ __launch_bounds__(256) void merge_ln_kernel(
    const float* __restrict__ part, float* __restrict__ residual,
    u16* __restrict__ h2, const float* __restrict__ w, const float* __restrict__ bia)
{
    int row = blockIdx.x; int tid = threadIdx.x;
    const size_t MN = (size_t)BL_*D_;
    __shared__ float sbuf[8];
    float v[3]; float s=0.f, ss=0.f;
    size_t base = (size_t)row*D_;
    #pragma unroll
    for (int j=0;j<3;j++){
        int c = tid + j*256;
        float o = part[base+c] + part[MN+base+c] + part[2*MN+base+c] + part[3*MN+base+c];
        float x = residual[base+c] + 0.5f*o;
        v[j]=x; s+=x; ss+=x*x;
        residual[base+c] = x;
    }
    for (int off=32; off; off>>=1){ s += __shfl_down(s,off); ss += __shfl_down(ss,off); }
    int wid = tid>>6, lane = tid&63;
    if (lane==0){ sbuf[wid]=s; sbuf[4+wid]=ss; }
    __syncthreads();
    if (tid==0){
        float S=sbuf[0]+sbuf[1]+sbuf[2]+sbuf[3];
        float SS=sbuf[4]+sbuf[5]+sbuf[6]+sbuf[7];
        float mean = S/(float)D_;
        float var = SS/(float)D_ - mean*mean;
        sbuf[0]=mean; sbuf[1]=rsqrtf(var+1e-5f);
    }
    __syncthreads();
    float mean=sbuf[0], inv=sbuf[1];
    #pragma unroll
    for (int j=0;j<3;j++){
        int c = tid + j*256;
        h2[base+c] = (u16)f2bf((v[j]-mean)*inv*w[c]+bia[c]);
    }
}

// ---- mlp2 partial reduce + bias -> xs[i]; residual += x; h = LN1[i+1](residual) ----
__global__ __launch_bounds__(256) void mlp2red_ln(
    const float* __restrict__ part, const float* __restrict__ b2,
    float* __restrict__ xs_out, float* __restrict__ residual,
    u16* __restrict__ hout, const float* __restrict__ w, const float* __restrict__ bia)
{
    int row = blockIdx.x; int tid = threadIdx.x;
    const size_t MN = (size_t)BL_*D_;
    __shared__ float sbuf[8];
    float v[3]; float s=0.f, ss=0.f;
    size_t base = (size_t)row*D_;
    #pragma unroll
    for (int j=0;j<3;j++){
        int c = tid + j*256;
        float x = part[base+c] + part[MN+base+c] + part[2*MN+base+c] + part[3*MN+base+c] + b2[c];
        xs_out[base+c] = x;
        float r = residual[base+c] + x;
        residual[base+c] = r;
        v[j]=r; s+=r; ss+=r*r;
    }
    for (int off=32; off; off>>=1){ s += __shfl_down(s,off); ss += __shfl_down(ss,off); }
    int wid = tid>>6, lane = tid&63;
    if (lane==0){ sbuf[wid]=s; sbuf[4+wid]=ss; }
    __syncthreads();
    if (tid==0){
        float S=sbuf[0]+sbuf[1]+sbuf[2]+sbuf[3];
        float SS=sbuf[4]+sbuf[5]+sbuf[6]+sbuf[7];
        float mean = S/(float)D_;
        float var = SS/(float)D_ - mean*mean;
        sbuf[0]=mean; sbuf[1]=rsqrtf(var+1e-5f);
    }
    __syncthreads();
    float mean=sbuf[0], inv=sbuf[1];
    #pragma unroll
    for (int j=0;j<3;j++){
        int c = tid + j*256;
        hout[base+c] = (u16)f2bf((v[j]-mean)*inv*w[c]+bia[c]);
    }
}

// ---- last layer: reduce + bias -> xs[5] and out[0] ----
__global__ __launch_bounds__(256) void mlp2red_final(
    const float* __restrict__ part, const float* __restrict__ b2,
    float* __restrict__ xs_out, float* __restrict__ out0)
{
    int idx = blockIdx.x*256 + threadIdx.x;
    if (idx >= BL_*D_) return;
    const size_t MN = (size_t)BL_*D_;
    int c = idx % D_;
    float x = part[idx] + part[MN+idx] + part[2*MN+idx] + part[3*MN+idx] + b2[c];
    xs_out[idx] = x;
    out0[idx] = x;
}

// ---------------- depthwise conv + SiLU, vectorized bf16x8 (xz is [BL][6144]) ----------------
__global__ __launch_bounds__(256) void conv_silu_v(
    const u16* __restrict__ xz, const float* __restrict__ conv_w,
    const float* __restrict__ conv_b, u16* __restrict__ xc, int layer)
{
    const int NG = DI_/8;
    int idx = blockIdx.x*256 + threadIdx.x;
    if (idx >= 2*BL_*NG) return;
    int g = idx % NG;
    int bl = (idx / NG) % BL_;
    int dir = idx / (NG*BL_);
    int b = bl / L_, p = bl % L_;
    int d0 = g*8;
    const float* wp = conv_w + ((size_t)(layer*2+dir)*DI_ + d0)*KC_;
    float w[8][4];
    #pragma unroll
    for (int d = 0; d < 8; ++d) {
        float4 t = ((const float4*)wp)[d];
        w[d][0]=t.x; w[d][1]=t.y; w[d][2]=t.z; w[d][3]=t.w;
    }
    float acc[8];
    const float* bp = conv_b + (size_t)(layer*2+dir)*DI_ + d0;
    #pragma unroll
    for (int d = 0; d < 8; ++d) acc[d] = bp[d];
    const u16* xp = xz + dir*(2*DI_) + d0;
    #pragma unroll
    for (int k = 0; k < KC_; ++k) {
        int q = (dir == 0) ? (p - 3 + k) : (p + 3 - k);
        if (q < 0 || q >= L_) continue;
        uint4 raw = *(const uint4*)(xp + (size_t)(b*L_+q)*NXZ_);
        const u16* xv = (const u16*)&raw;
        #pragma unroll
        for (int d = 0; d < 8; ++d) acc[d] = fmaf(bf2f(xv[d]), w[d][k], acc[d]);
    }
    u16 o[8];
    #pragma unroll
    for (int d = 0; d < 8; ++d) o[d] = (u16)f2bf(siluf(acc[d]));
    *(uint4*)(xc + (size_t)dir*BL_*DI_ + (size_t)bl*DI_ + d0) = *(uint4*)o;
}

// ---------------- chunked scan, thread-per-d with 16 n-states ----------------
__global__ __launch_bounds__(256) void scan_part2(
    const float* __restrict__ dts, const u16* __restrict__ xc,
    const float* __restrict__ xdbl, const float* __restrict__ A_log,
    float* __restrict__ hp, float* __restrict__ Pp, int layer)
{
    int bid = blockIdx.x;
    int dblk = bid % (DI_/256);
    int chunk = (bid/(DI_/256)) % CH2_;
    int b = (bid/((DI_/256)*CH2_)) % B_;
    int dir = bid / ((DI_/256)*CH2_*B_);
    int tid = threadIdx.x;
    int d = dblk*256 + tid;
    __shared__ float sB[S_][16];
    for (int i = tid; i < S_*16; i += 256) {
        int s = i >> 4, n = i & 15;
        int sidx = chunk*S_ + s;
        int p = dir ? (L_-1-sidx) : sidx;
        sB[s][n] = xdbl[(size_t)dir*BL_*XD_ + (size_t)(b*L_+p)*XD_ + 48 + n];
    }
    __syncthreads();
    float Av[16];
    const float* Ap = A_log + (((size_t)layer*2+dir)*DI_ + d)*NS_;
    #pragma unroll
    for (int n = 0; n < 16; ++n) Av[n] = -__expf(Ap[n]);
    float h[16] = {};
    float P[16];
    #pragma unroll
    for (int n = 0; n < 16; ++n) P[n] = 1.f;
    const float* dtp = dts + ((((size_t)layer*2+dir)*B_ + b)*L_)*DI_ + d;
    const u16*  xcp = xc + (size_t)dir*BL_*DI_ + (size_t)b*L_*DI_ + d;
    #pragma unroll 2
    for (int s = 0; s < S_; ++s) {
        int sidx = chunk*S_ + s;
        int p = dir ? (L_-1-sidx) : sidx;
        float dtv = dtp[(size_t)sidx*DI_];
        float xv  = bf2f(xcp[(size_t)p*DI_]);
        float u = dtv * xv;
        #pragma unroll
        for (int n = 0; n < 16; ++n) {
            float dA = __expf(dtv*Av[n]);
            P[n] *= dA;
            h[n] = fmaf(dA, h[n], u*sB[s][n]);
        }
    }
    size_t o = (((size_t)(dir*B_+b)*CH2_ + chunk)*DI_ + d)*16;
    #pragma unroll
    for (int n = 0; n < 16; n += 4) {
        *(float4*)&hp[o+n] = make_float4(h[n],h[n+1],h[n+2],h[n+3]);
        *(float4*)&Pp[o+n] = make_float4(P[n],P[n+1],P[n+2],P[n+3]);
    }
}

__global__ __launch_bounds__(256) void scan_combine(
    float* __restrict__ hp, const float* __restrict__ Pp)
{
    int bid = blockIdx.x;
    int seg = bid % (DI_*16/256);
    int b = (bid/(DI_*16/256)) % B_;
    int dir = bid / ((DI_*16/256)*B_);
    int idx = seg*256 + threadIdx.x;
    size_t base = ((size_t)(dir*B_+b)*CH2_)*DI_*16 + idx;
    float h = 0.f;
    for (int c = 0; c < CH2_; ++c) {
        size_t i = base + (size_t)c*DI_*16;
        float Pv = Pp[i], hl = hp[i];
        hp[i] = h;
        h = fmaf(Pv, h, hl);
    }
}

// phase 3: recompute with h_init, y = C.h, fused gate -> yb bf16 (z from xz [BL][6144])
__global__ __launch_bounds__(256) void scan_final2(
    const float* __restrict__ dts, const u16* __restrict__ xc,
    const float* __restrict__ xdbl, const float* __restrict__ A_log,
    const float* __restrict__ hp, const u16* __restrict__ xz,
    const float* __restrict__ Dp, u16* __restrict__ yb, int layer)
{
    int bid = blockIdx.x;
    int dblk = bid % (DI_/256);
    int chunk = (bid/(DI_/256)) % CH2_;
    int b = (bid/((DI_/256)*CH2_)) % B_;
    int dir = bid / ((DI_/256)*CH2_*B_);
    int tid = threadIdx.x;
    int d = dblk*256 + tid;
    __shared__ float sB[S_][16], sC[S_][16];
    for (int i = tid; i < S_*16*2; i += 256) {
        int which = i >= S_*16;
        int j = i & (S_*16-1);
        int s = j >> 4, n = j & 15;
        int sidx = chunk*S_ + s;
        int p = dir ? (L_-1-sidx) : sidx;
        float v = xdbl[(size_t)dir*BL_*XD_ + (size_t)(b*L_+p)*XD_ + (which?64:48) + n];
        if (which) sC[s][n] = v; else sB[s][n] = v;
    }
    __syncthreads();
    float Av[16];
    const float* Ap = A_log + (((size_t)layer*2+dir)*DI_ + d)*NS_;
    #pragma unroll
    for (int n = 0; n < 16; ++n) Av[n] = -__expf(Ap[n]);
    float h[16];
    {
        size_t o = (((size_t)(dir*B_+b)*CH2_ + chunk)*DI_ + d)*16;
        #pragma unroll
        for (int n = 0; n < 16; n += 4) {
            float4 t = *(const float4*)&hp[o+n];
            h[n]=t.x; h[n+1]=t.y; h[n+2]=t.z; h[n+3]=t.w;
        }
    }
    float Dpv = Dp[(size_t)(layer*2+dir)*DI_ + d];
    const float* dtp = dts + ((((size_t)layer*2+dir)*B_ + b)*L_)*DI_ + d;
    const u16*  xcp = xc + (size_t)dir*BL_*DI_ + (size_t)b*L_*DI_ + d;
    const u16*  zp  = xz + (size_t)b*L_*NXZ_ + dir*(2*DI_) + DI_ + d;
    u16* yp = yb + (size_t)dir*BL_*DI_ + (size_t)b*L_*DI_ + d;
    #pragma unroll 2
    for (int s = 0; s < S_; ++s) {
        int sidx = chunk*S_ + s;
        int p = dir ? (L_-1-sidx) : sidx;
        float dtv = dtp[(size_t)sidx*DI_];
        float xv  = bf2f(xcp[(size_t)p*DI_]);
        float u = dtv * xv;
        float y = 0.f;
        #pragma unroll
        for (int n = 0; n < 16; ++n) {
            float dA = __expf(dtv*Av[n]);
            h[n] = fmaf(dA, h[n], u*sB[s][n]);
            y = fmaf(h[n], sC[s][n], y);
        }
        float z = bf2f(zp[(size_t)p*NXZ_]);
        float v = y + xv*Dpv;
        yp[(size_t)p*DI_] = (u16)f2bf(v * siluf(z));
    }
}

extern "C" void kernel_launch(void* const* d_in, const int* in_sizes, int n_in,
                              void* d_out, int out_size, void* d_ws, size_t ws_size,
                              hipStream_t stream)
{
    const float* x_in    = (const float*)d_in[0];
    const float* ln1_w   = (const float*)d_in[1];
    const float* ln1_b   = (const float*)d_in[2];
    const float* ln2_w   = (const float*)d_in[3];
    const float* ln2_b   = (const float*)d_in[4];
    const float* in_w    = (const float*)d_in[5];
    const float* conv_w  = (const float*)d_in[6];
    const float* conv_b  = (const float*)d_in[7];
    const float* xproj_w = (const float*)d_in[8];
    const float* dtproj_w= (const float*)d_in[9];
    const float* dtproj_b= (const float*)d_in[10];
    const float* A_log   = (const float*)d_in[11];
    const float* D_param = (const float*)d_in[12];
    const float* out_w   = (const float*)d_in[13];
    const float* mlp_w1  = (const float*)d_in[14];
    const float* mlp_b1  = (const float*)d_in[15];
    const float* mlp_w2  = (const float*)d_in[16];
    const float* mlp_b2  = (const float*)d_in[17];

    float* out = (float*)d_out;
    char* base = (char*)d_ws;
    float* res    = (float*)base;  base += (size_t)BL_*D_*4;
    u16*   xz     = (u16*)base;    base += (size_t)BL_*NXZ_*2;     // [BL][6144]
    u16*   xc_bf  = (u16*)base;    base += (size_t)2*BL_*DI_*2;
    float* xdbl   = (float*)base;  base += (size_t)2*BL_*XD_*4;
    u16*   dtlr_bf= (u16*)base;    base += (size_t)2*BL_*64*2;
    float* hp     = (float*)base;  base += (size_t)2*B_*CH2_*DI_*16*4;
    float* part   = (float*)base;  base += (size_t)4*BL_*D_*4;     // also Pp / xproj partials
    u16*   yb_bf  = (u16*)base;    base += (size_t)2*BL_*DI_*2;
    u16*   h_bf   = (u16*)base;    base += (size_t)BL_*D_*2;
    u16*   h2_bf  = (u16*)base;    base += (size_t)BL_*D_*2;
    u16*   hid_bf = (u16*)base;    base += (size_t)BL_*FF_*2;
    u16*   w_in   = (u16*)base;    base += (size_t)2*(2*DI_)*D_*2;
    u16*   w_out  = (u16*)base;    base += (size_t)2*D_*DI_*2;
    u16*   w_m1   = (u16*)base;    base += (size_t)FF_*D_*2;
    u16*   w_m2   = (u16*)base;    base += (size_t)D_*FF_*2;
    u16*   w_xp   = (u16*)base;    base += (size_t)2*XD_*DI_*2;
    u16*   w_dt   = (u16*)base;    base += (size_t)2*DI_*64*2;

    float* Pp = part;
    float* dts_base = out + OUT_DTS;

    ln_res_kernel<<<BL_, 256, 0, stream>>>(x_in, res, h_bf, ln1_w, ln1_b);

    for (int i = 0; i < DEPTH_; ++i) {
        cvt_weights<<<dim3(4608, 6), 256, 0, stream>>>(
            in_w  + (size_t)i*2*(2*DI_)*D_, out_w + (size_t)i*2*D_*DI_,
            mlp_w1+ (size_t)i*FF_*D_,       mlp_w2+ (size_t)i*D_*FF_,
            xproj_w + (size_t)i*2*80*DI_,   dtproj_w + (size_t)i*2*DI_*48,
            w_in, w_out, w_m1, w_m2, w_xp, w_dt);

        // in_proj (folded dirs): xz[BL][6144] = h @ [in_w0;in_w1]^T
        dim3 gIn(BL_/128, NXZ_/128, 1);
        gemm_bf16<0,1><<<gIn, 256, 0, stream>>>(h_bf, w_in, nullptr, xz, nullptr, nullptr, 0,
            BL_, NXZ_, D_, 1, 0L, 0L, 0L, 0L);

        conv_silu_v<<<(2*BL_*(DI_/8)+255)/256, 256, 0, stream>>>(xz, conv_w, conv_b, xc_bf, i);

        // xproj: split-K=8 partials -> fused reduce + dtlr
        dim3 gXp(BL_/128, 1, 2*8);
        gemm_bf16<0,0><<<gXp, 256, 0, stream>>>(xc_bf, w_xp, part, nullptr, nullptr, nullptr, 0,
            BL_, XD_, DI_, 8, (long)BL_*DI_, (long)XD_*DI_, (long)BL_*XD_, 0L);
        xpred_dtlr<<<(2*BL_*XD_+255)/256, 256, 0, stream>>>(part, xdbl, dtlr_bf, out, i);

        // dtproj: softplus -> flipped dts output (scan reads from there)
        dim3 gDt(BL_/128, DI_/128, 2);
        gemm_bf16<4,0><<<gDt, 256, 0, stream>>>(dtlr_bf, w_dt, nullptr, nullptr,
            dtproj_b + (size_t)i*2*DI_, dts_base, i,
            BL_, DI_, 64, 1, (long)BL_*64, (long)DI_*64, 0L, (long)DI_);

        // chunked scan (Pp aliases part region)
        scan_part2<<<2*B_*CH2_*(DI_/256), 256, 0, stream>>>(dts_base, xc_bf, xdbl, A_log, hp, Pp, i);
        scan_combine<<<2*B_*(DI_*16/256), 256, 0, stream>>>(hp, Pp);
        scan_final2<<<2*B_*CH2_*(DI_/256), 256, 0, stream>>>(dts_base, xc_bf, xdbl, A_log, hp,
            xz, D_param, yb_bf, i);

        // out_proj: split-K=2 partials (4 slices) -> merge_ln
        dim3 gOut(BL_/128, D_/128, 2*2);
        gemm_bf16<0,0><<<gOut, 256, 0, stream>>>(yb_bf, w_out, part, nullptr, nullptr, nullptr, 0,
            BL_, D_, DI_, 2, (long)BL_*DI_, (long)D_*DI_, (long)BL_*D_, 0L);
        merge_ln_kernel<<<BL_, 256, 0, stream>>>(part, res, h2_bf,
            ln2_w + (size_t)i*D_, ln2_b + (size_t)i*D_);

        // mlp1: gelu -> bf16 hid
        dim3 gM1(BL_/128, FF_/128, 1);
        gemm_bf16<2,1><<<gM1, 256, 0, stream>>>(h2_bf, w_m1, nullptr, hid_bf,
            mlp_b1 + (size_t)i*FF_, nullptr, 0, BL_, FF_, D_, 1, 0L, 0L, (long)BL_*FF_, 0L);

        // mlp2: split-K=4 partials
        dim3 gM2(BL_/128, D_/128, 4);
        gemm_bf16<0,0><<<gM2, 256, 0, stream>>>(hid_bf, w_m2, part, nullptr, nullptr, nullptr, 0,
            BL_, D_, FF_, 4, 0L, 0L, (long)BL_*D_, 0L);

        if (i < DEPTH_-1) {
            mlp2red_ln<<<BL_, 256, 0, stream>>>(part, mlp_b2 + (size_t)i*D_,
                out + OUT_XS + (size_t)i*BL_*D_, res, h_bf,
                ln1_w + (size_t)(i+1)*D_, ln1_b + (size_t)(i+1)*D_);
        } else {
            mlp2red_final<<<(BL_*D_+255)/256, 256, 0, stream>>>(part, mlp_b2 + (size_t)i*D_,
                out + OUT_XS + (size_t)i*BL_*D_, out);
        }
    }
}